// Round 1
// baseline (1615.799 us; speedup 1.0000x reference)
//
#include <hip/hip_runtime.h>
#include <hip/hip_bf16.h>
#include <math.h>

// Geometry
#define WPD 266   // padded H=W
#define HO1 262   // after 5x5
#define HO2 260
#define HO3 258
#define HO4 256

// ---------------- pad fill: xp = pad(x, 5, value=0.5) ----------------
__global__ void pad_fill_kernel(const float* __restrict__ x, float* __restrict__ xp,
                                int bBase, int gc) {
  size_t total = (size_t)gc * WPD * WPD;
  for (size_t idx = (size_t)blockIdx.x * blockDim.x + threadIdx.x; idx < total;
       idx += (size_t)gridDim.x * blockDim.x) {
    size_t zb = idx / (WPD * WPD);
    int rem = (int)(idx % (WPD * WPD));
    int y = rem / WPD, xx = rem % WPD;
    float v = 0.5f;
    if (y >= 5 && y < 261 && xx >= 5 && xx < 261)
      v = x[((size_t)(bBase + zb) * 256 + (y - 5)) * 256 + (xx - 5)];
    xp[idx] = v;
  }
}

// ---------------- border extrapolation (sequential rings i=5..1) ----------------
// One block per batch image. Within a ring: the 4 edge fills read only pixels
// not written this ring (verified against the JAX .at.set ordering), so they
// run in parallel; corners depend on edges -> barrier; 3 sequential ops/corner.
__global__ void extrap_kernel(float* __restrict__ xp) {
  const int W = WPD, H = WPD;
  float* p = xp + (size_t)blockIdx.x * W * W;
  for (int i = 5; i >= 1; --i) {
    int ip = i + 1, im = i - 1;
    int L = W - 2 * ip;  // edge output length
    for (int t = threadIdx.x; t < 4 * L; t += blockDim.x) {
      int e = t / L, j = t % L;
      float a;
      if (e == 0) {        // top: row im <- row i
        a = (p[i * W + i + j] + p[i * W + i + j + 1] + p[i * W + i + j + 2]) / 3.0f;
        p[im * W + ip + j] = a > 0.3f ? 1.0f : a;
      } else if (e == 1) { // bottom: row H-i <- row H-ip
        const float* r = p + (H - ip) * W;
        a = (r[i + j] + r[i + j + 1] + r[i + j + 2]) / 3.0f;
        p[(H - i) * W + ip + j] = a > 0.3f ? 1.0f : a;
      } else if (e == 2) { // left: col im <- col i
        a = (p[(i + j) * W + i] + p[(i + j + 1) * W + i] + p[(i + j + 2) * W + i]) / 3.0f;
        p[(ip + j) * W + im] = a > 0.3f ? 1.0f : a;
      } else {             // right: col W-i <- col W-ip
        a = (p[(i + j) * W + (W - ip)] + p[(i + j + 1) * W + (W - ip)] +
             p[(i + j + 2) * W + (W - ip)]) / 3.0f;
        p[(ip + j) * W + (W - i)] = a > 0.3f ? 1.0f : a;
      }
    }
    __syncthreads();
    if (threadIdx.x < 4) {
      int c = threadIdx.x;
      int cx, cy, nx, ny;
      if (c == 0)      { cx = im;    cy = im;    nx = 1;  ny = 1;  }
      else if (c == 1) { cx = W - i; cy = im;    nx = -1; ny = 1;  }
      else if (c == 2) { cx = W - i; cy = H - i; nx = -1; ny = -1; }
      else             { cx = im;    cy = H - i; nx = 1;  ny = -1; }
      int cxp = cx + nx, cyp = cy + ny;
      p[cy * W + cxp] = (p[cyp * W + cxp] + p[cy * W + cx + 2 * nx]) * 0.5f;
      p[cyp * W + cx] = (p[cyp * W + cxp] + p[(cy + 2 * ny) * W + cx]) * 0.5f;
      p[cy * W + cx]  = (p[cy * W + cxp] + p[cyp * W + cx]) * 0.5f;
    }
    __syncthreads();
  }
}

// ---------------- conv1: 5x5, 1 -> 64, relu, f32 in -> bf16 out ----------------
__global__ __launch_bounds__(256) void conv1_kernel(
    const float* __restrict__ xp, __hip_bfloat16* __restrict__ h1,
    const float* __restrict__ W1, const float* __restrict__ b1) {
  const int HIN = WPD, HO = HO1;
  int zb = blockIdx.z;
  const float* p = xp + (size_t)zb * HIN * HIN;
  int tx = threadIdx.x & 15, ty = threadIdx.x >> 4;
  int x0 = blockIdx.x * 16, y0 = blockIdx.y * 16;
  __shared__ float tile[20][20];
  for (int idx = threadIdx.x; idx < 20 * 20; idx += 256) {
    int r = idx / 20, c = idx % 20;
    int yy = min(y0 + r, HIN - 1), xx = min(x0 + c, HIN - 1);
    tile[r][c] = p[yy * HIN + xx];
  }
  __syncthreads();
  float v[25];
#pragma unroll
  for (int ky = 0; ky < 5; ++ky)
#pragma unroll
    for (int kx = 0; kx < 5; ++kx) v[ky * 5 + kx] = tile[ty + ky][tx + kx];
  int ox = x0 + tx, oy = y0 + ty;
  bool valid = (ox < HO) && (oy < HO);
  __hip_bfloat16* outp = h1 + (size_t)zb * 64 * HO * HO;
#pragma unroll 1
  for (int oc0 = 0; oc0 < 64; oc0 += 16) {
    float acc[16];
#pragma unroll
    for (int o = 0; o < 16; ++o) acc[o] = b1[oc0 + o];  // uniform -> s_load
#pragma unroll
    for (int o = 0; o < 16; ++o) {
      const float* wp = W1 + (size_t)(oc0 + o) * 25;    // uniform -> s_load
#pragma unroll
      for (int k = 0; k < 25; ++k) acc[o] = fmaf(wp[k], v[k], acc[o]);
    }
    if (valid) {
#pragma unroll
      for (int o = 0; o < 16; ++o) {
        float r = acc[o] > 0.0f ? acc[o] : 0.0f;
        outp[(size_t)(oc0 + o) * HO * HO + (size_t)oy * HO + ox] = __float2bfloat16(r);
      }
    }
  }
}

// ---------------- generic 3x3 conv: CIN -> COUT, relu, bf16 -> bf16 ----------------
template <int CIN, int COUT, int HIN>
__global__ __launch_bounds__(256) void conv3x3_kernel(
    const __hip_bfloat16* __restrict__ in, __hip_bfloat16* __restrict__ out,
    const float* __restrict__ Wt, const float* __restrict__ bias) {
  const int HO = HIN - 2;
  int zb = blockIdx.z;
  const __hip_bfloat16* ipb = in + (size_t)zb * CIN * HIN * HIN;
  __hip_bfloat16* opb = out + (size_t)zb * COUT * HO * HO;
  int tx = threadIdx.x & 15, ty = threadIdx.x >> 4;
  int x0 = blockIdx.x * 16, y0 = blockIdx.y * 16;
  __shared__ float tile[18][18];
  float acc[COUT];
#pragma unroll
  for (int o = 0; o < COUT; ++o) acc[o] = bias[o];  // uniform -> s_load
#pragma unroll 1
  for (int cin = 0; cin < CIN; ++cin) {
    __syncthreads();  // previous tile fully consumed
    const __hip_bfloat16* pl = ipb + (size_t)cin * HIN * HIN;
    for (int idx = threadIdx.x; idx < 18 * 18; idx += 256) {
      int r = idx / 18, c = idx % 18;
      int yy = min(y0 + r, HIN - 1), xx = min(x0 + c, HIN - 1);
      tile[r][c] = __bfloat162float(pl[(size_t)yy * HIN + xx]);
    }
    __syncthreads();
    float v[9];
#pragma unroll
    for (int ky = 0; ky < 3; ++ky)
#pragma unroll
      for (int kx = 0; kx < 3; ++kx) v[ky * 3 + kx] = tile[ty + ky][tx + kx];
    const float* wb = Wt + (size_t)cin * 9;
#pragma unroll
    for (int o = 0; o < COUT; ++o) {
      const float* wp = wb + (size_t)o * CIN * 9;  // uniform -> s_load
#pragma unroll
      for (int k = 0; k < 9; ++k) acc[o] = fmaf(wp[k], v[k], acc[o]);
    }
  }
  int ox = x0 + tx, oy = y0 + ty;
  if (ox < HO && oy < HO) {
#pragma unroll
    for (int o = 0; o < COUT; ++o) {
      float r = acc[o] > 0.0f ? acc[o] : 0.0f;
      opb[(size_t)o * HO * HO + (size_t)oy * HO + ox] = __float2bfloat16(r);
    }
  }
}

// ---------------- conv4: 3x3, 32 -> 16, sigmoid + pixel_shuffle(r=4) ----------------
__global__ __launch_bounds__(256) void conv4_kernel(
    const __hip_bfloat16* __restrict__ in, float* __restrict__ out,
    const float* __restrict__ Wt, const float* __restrict__ bias, int bBase) {
  const int CIN = 32, HIN = HO3, HO = HO4;
  int zb = blockIdx.z;
  const __hip_bfloat16* ipb = in + (size_t)zb * CIN * HIN * HIN;
  int tx = threadIdx.x & 15, ty = threadIdx.x >> 4;
  int x0 = blockIdx.x * 16, y0 = blockIdx.y * 16;
  __shared__ float tile[18][18];
  float acc[16];
#pragma unroll
  for (int o = 0; o < 16; ++o) acc[o] = bias[o];
#pragma unroll 1
  for (int cin = 0; cin < CIN; ++cin) {
    __syncthreads();
    const __hip_bfloat16* pl = ipb + (size_t)cin * HIN * HIN;
    for (int idx = threadIdx.x; idx < 18 * 18; idx += 256) {
      int r = idx / 18, c = idx % 18;
      int yy = min(y0 + r, HIN - 1), xx = min(x0 + c, HIN - 1);
      tile[r][c] = __bfloat162float(pl[(size_t)yy * HIN + xx]);
    }
    __syncthreads();
    float v[9];
#pragma unroll
    for (int ky = 0; ky < 3; ++ky)
#pragma unroll
      for (int kx = 0; kx < 3; ++kx) v[ky * 3 + kx] = tile[ty + ky][tx + kx];
    const float* wb = Wt + (size_t)cin * 9;
#pragma unroll
    for (int o = 0; o < 16; ++o) {
      const float* wp = wb + (size_t)o * CIN * 9;
#pragma unroll
      for (int k = 0; k < 9; ++k) acc[o] = fmaf(wp[k], v[k], acc[o]);
    }
  }
  int ox = x0 + tx, oy = y0 + ty;  // grid is exact 16x16 -> always valid
  float* ob = out + (size_t)(bBase + zb) * 1024 * 1024;
#pragma unroll
  for (int i = 0; i < 4; ++i) {
    float4 vv;
    vv.x = 1.0f / (1.0f + expf(-acc[i * 4 + 0]));
    vv.y = 1.0f / (1.0f + expf(-acc[i * 4 + 1]));
    vv.z = 1.0f / (1.0f + expf(-acc[i * 4 + 2]));
    vv.w = 1.0f / (1.0f + expf(-acc[i * 4 + 3]));
    *reinterpret_cast<float4*>(&ob[(size_t)(oy * 4 + i) * 1024 + ox * 4]) = vv;
  }
}

extern "C" void kernel_launch(void* const* d_in, const int* in_sizes, int n_in,
                              void* d_out, int out_size, void* d_ws, size_t ws_size,
                              hipStream_t stream) {
  const float* x  = (const float*)d_in[0];
  const float* W1 = (const float*)d_in[1];
  const float* b1 = (const float*)d_in[2];
  const float* W2 = (const float*)d_in[3];
  const float* b2 = (const float*)d_in[4];
  const float* W3 = (const float*)d_in[5];
  const float* b3 = (const float*)d_in[6];
  const float* W4 = (const float*)d_in[7];
  const float* b4 = (const float*)d_in[8];
  float* out = (float*)d_out;

  const size_t xp_sz = (size_t)WPD * WPD * sizeof(float);            // 283,024 B
  const size_t h1_sz = (size_t)64 * HO1 * HO1 * sizeof(__hip_bfloat16);
  const size_t h2_sz = (size_t)32 * HO2 * HO2 * sizeof(__hip_bfloat16);
  const size_t h3_sz = (size_t)32 * HO3 * HO3 * sizeof(__hip_bfloat16);
  const size_t per_b = xp_sz + h1_sz + h2_sz + h3_sz;                // ~17.7 MB/batch

  int g = (int)(ws_size / per_b);
  if (g > 16) g = 16;
  if (g < 1) g = 1;  // assume ws_size >= ~18 MB

  char* base = (char*)d_ws;
  float* xp = (float*)base;
  __hip_bfloat16* h1 = (__hip_bfloat16*)(base + (size_t)g * xp_sz);
  __hip_bfloat16* h2 = (__hip_bfloat16*)((char*)h1 + (size_t)g * h1_sz);
  __hip_bfloat16* h3 = (__hip_bfloat16*)((char*)h2 + (size_t)g * h2_sz);

  for (int bBase = 0; bBase < 16; bBase += g) {
    int gc = min(g, 16 - bBase);
    size_t tot = (size_t)gc * WPD * WPD;
    int fillBlocks = (int)min((tot + 255) / 256, (size_t)2048);
    pad_fill_kernel<<<fillBlocks, 256, 0, stream>>>(x, xp, bBase, gc);
    extrap_kernel<<<gc, 256, 0, stream>>>(xp);
    conv1_kernel<<<dim3(17, 17, gc), 256, 0, stream>>>(xp, h1, W1, b1);
    conv3x3_kernel<64, 32, HO1><<<dim3(17, 17, gc), 256, 0, stream>>>(h1, h2, W2, b2);
    conv3x3_kernel<32, 32, HO2><<<dim3(17, 17, gc), 256, 0, stream>>>(h2, h3, W3, b3);
    conv4_kernel<<<dim3(16, 16, gc), 256, 0, stream>>>(h3, out, W4, b4, bBase);
  }
}

// Round 2
// 399.603 us; speedup vs baseline: 4.0435x; 4.0435x over previous
//
#include <hip/hip_runtime.h>
#include <hip/hip_bf16.h>
#include <math.h>

// Geometry
#define WPD 266   // padded H=W
#define HO1 262   // after 5x5
#define HO2 260
#define HO3 258
#define HO4 256

typedef __attribute__((ext_vector_type(8))) short short8_t;
typedef __attribute__((ext_vector_type(4))) float float4_t;

// ---------------- pad fill: xp = pad(x, 5, value=0.5) ----------------
__global__ void pad_fill_kernel(const float* __restrict__ x, float* __restrict__ xp,
                                int bBase, int gc) {
  size_t total = (size_t)gc * WPD * WPD;
  for (size_t idx = (size_t)blockIdx.x * blockDim.x + threadIdx.x; idx < total;
       idx += (size_t)gridDim.x * blockDim.x) {
    size_t zb = idx / (WPD * WPD);
    int rem = (int)(idx % (WPD * WPD));
    int y = rem / WPD, xx = rem % WPD;
    float v = 0.5f;
    if (y >= 5 && y < 261 && xx >= 5 && xx < 261)
      v = x[((size_t)(bBase + zb) * 256 + (y - 5)) * 256 + (xx - 5)];
    xp[idx] = v;
  }
}

// ---------------- border extrapolation (sequential rings i=5..1) ----------------
__global__ void extrap_kernel(float* __restrict__ xp) {
  const int W = WPD, H = WPD;
  float* p = xp + (size_t)blockIdx.x * W * W;
  for (int i = 5; i >= 1; --i) {
    int ip = i + 1, im = i - 1;
    int L = W - 2 * ip;
    for (int t = threadIdx.x; t < 4 * L; t += blockDim.x) {
      int e = t / L, j = t % L;
      float a;
      if (e == 0) {
        a = (p[i * W + i + j] + p[i * W + i + j + 1] + p[i * W + i + j + 2]) / 3.0f;
        p[im * W + ip + j] = a > 0.3f ? 1.0f : a;
      } else if (e == 1) {
        const float* r = p + (H - ip) * W;
        a = (r[i + j] + r[i + j + 1] + r[i + j + 2]) / 3.0f;
        p[(H - i) * W + ip + j] = a > 0.3f ? 1.0f : a;
      } else if (e == 2) {
        a = (p[(i + j) * W + i] + p[(i + j + 1) * W + i] + p[(i + j + 2) * W + i]) / 3.0f;
        p[(ip + j) * W + im] = a > 0.3f ? 1.0f : a;
      } else {
        a = (p[(i + j) * W + (W - ip)] + p[(i + j + 1) * W + (W - ip)] +
             p[(i + j + 2) * W + (W - ip)]) / 3.0f;
        p[(ip + j) * W + (W - i)] = a > 0.3f ? 1.0f : a;
      }
    }
    __syncthreads();
    if (threadIdx.x < 4) {
      int c = threadIdx.x;
      int cx, cy, nx, ny;
      if (c == 0)      { cx = im;    cy = im;    nx = 1;  ny = 1;  }
      else if (c == 1) { cx = W - i; cy = im;    nx = -1; ny = 1;  }
      else if (c == 2) { cx = W - i; cy = H - i; nx = -1; ny = -1; }
      else             { cx = im;    cy = H - i; nx = 1;  ny = -1; }
      int cxp = cx + nx, cyp = cy + ny;
      p[cy * W + cxp] = (p[cyp * W + cxp] + p[cy * W + cx + 2 * nx]) * 0.5f;
      p[cyp * W + cx] = (p[cyp * W + cxp] + p[(cy + 2 * ny) * W + cx]) * 0.5f;
      p[cy * W + cx]  = (p[cy * W + cxp] + p[cyp * W + cx]) * 0.5f;
    }
    __syncthreads();
  }
}

// ---------------- conv1: 5x5, 1 -> 64, relu, f32 in -> bf16 NHWC out ----------------
__global__ __launch_bounds__(256) void conv1_kernel(
    const float* __restrict__ xp, __hip_bfloat16* __restrict__ h1,
    const float* __restrict__ W1, const float* __restrict__ b1) {
  const int HIN = WPD, HO = HO1;
  int zb = blockIdx.z;
  const float* p = xp + (size_t)zb * HIN * HIN;
  int tx = threadIdx.x & 15, ty = threadIdx.x >> 4;
  int x0 = blockIdx.x * 16, y0 = blockIdx.y * 16;
  __shared__ float tile[20][20];
  for (int idx = threadIdx.x; idx < 20 * 20; idx += 256) {
    int r = idx / 20, c = idx % 20;
    int yy = min(y0 + r, HIN - 1), xx = min(x0 + c, HIN - 1);
    tile[r][c] = p[yy * HIN + xx];
  }
  __syncthreads();
  float v[25];
#pragma unroll
  for (int ky = 0; ky < 5; ++ky)
#pragma unroll
    for (int kx = 0; kx < 5; ++kx) v[ky * 5 + kx] = tile[ty + ky][tx + kx];
  int ox = x0 + tx, oy = y0 + ty;
  bool valid = (ox < HO) && (oy < HO);
  __hip_bfloat16* outp = h1 + (size_t)zb * HO * HO * 64;
  size_t obase = ((size_t)oy * HO + ox) * 64;
#pragma unroll 1
  for (int oc0 = 0; oc0 < 64; oc0 += 16) {
    float acc[16];
#pragma unroll
    for (int o = 0; o < 16; ++o) acc[o] = b1[oc0 + o];
#pragma unroll
    for (int o = 0; o < 16; ++o) {
      const float* wp = W1 + (size_t)(oc0 + o) * 25;  // uniform -> s_load
#pragma unroll
      for (int k = 0; k < 25; ++k) acc[o] = fmaf(wp[k], v[k], acc[o]);
    }
    if (valid) {
      short8_t pk0, pk1;
#pragma unroll
      for (int o = 0; o < 8; ++o) {
        float r = acc[o] > 0.0f ? acc[o] : 0.0f;
        __hip_bfloat16 h = __float2bfloat16(r);
        pk0[o] = *reinterpret_cast<short*>(&h);
      }
#pragma unroll
      for (int o = 0; o < 8; ++o) {
        float r = acc[8 + o] > 0.0f ? acc[8 + o] : 0.0f;
        __hip_bfloat16 h = __float2bfloat16(r);
        pk1[o] = *reinterpret_cast<short*>(&h);
      }
      *reinterpret_cast<short8_t*>(outp + obase + oc0) = pk0;
      *reinterpret_cast<short8_t*>(outp + obase + oc0 + 8) = pk1;
    }
  }
}

// ---------------- weight repack for MFMA B-fragments ----------------
// Wr[t][c][n][lane][j] = bf16(W[oc = n*16 + (lane&15)][ic = c*32 + (lane>>4)*8 + j][t])
__global__ void repack_w(const float* __restrict__ W, __hip_bfloat16* __restrict__ Wr,
                         int CIN, int COUT) {
  int NC = CIN / 32, NF = COUT / 16;
  int total = 9 * NC * NF * 512;
  for (int idx = blockIdx.x * blockDim.x + threadIdx.x; idx < total;
       idx += gridDim.x * blockDim.x) {
    int j = idx & 7, l = (idx >> 3) & 63;
    int rest = idx >> 9;
    int n = rest % NF; rest /= NF;
    int c = rest % NC; int t = rest / NC;
    int oc = n * 16 + (l & 15);
    int ic = c * 32 + (l >> 4) * 8 + j;
    Wr[idx] = __float2bfloat16(W[((size_t)oc * CIN + ic) * 9 + t]);
  }
}

// ---------------- 3x3 conv via MFMA implicit GEMM, NHWC bf16 ----------------
// Block: 16x16 spatial outputs x COUT channels. 4 waves x 4 output rows.
// A-fragments read directly from global (L1/L2 serve 9-tap reuse). No LDS.
template <int CIN, int COUT, int HIN>
__global__ __launch_bounds__(256) void conv3x3_mfma(
    const __hip_bfloat16* __restrict__ in, __hip_bfloat16* __restrict__ out,
    const __hip_bfloat16* __restrict__ wb, const float* __restrict__ bias) {
  constexpr int HO = HIN - 2;
  constexpr int NC = CIN / 32;
  constexpr int NF = COUT / 16;
  const int zb = blockIdx.z;
  const __hip_bfloat16* ip = in + (size_t)zb * HIN * HIN * CIN;
  __hip_bfloat16* op = out + (size_t)zb * HO * HO * COUT;
  const int lane = threadIdx.x & 63;
  const int wave = threadIdx.x >> 6;
  const int x0 = blockIdx.x * 16;
  const int y = blockIdx.y * 16 + wave * 4;  // first of this wave's 4 output rows

  int aoff[3];
#pragma unroll
  for (int kx = 0; kx < 3; ++kx) {
    int px = x0 + (lane & 15) + kx;
    px = px < HIN - 1 ? px : HIN - 1;
    aoff[kx] = px * CIN + (lane >> 4) * 8;
  }
  int rowoff[6];
#pragma unroll
  for (int r = 0; r < 6; ++r) {
    int yy = y + r; yy = yy < HIN - 1 ? yy : HIN - 1;
    rowoff[r] = yy * (HIN * CIN);
  }
  float bv[NF];
#pragma unroll
  for (int n = 0; n < NF; ++n) bv[n] = bias[n * 16 + (lane & 15)];
  float4_t acc[4][NF];
#pragma unroll
  for (int m = 0; m < 4; ++m)
#pragma unroll
    for (int n = 0; n < NF; ++n) acc[m][n] = {bv[n], bv[n], bv[n], bv[n]};

#pragma unroll
  for (int t = 0; t < 9; ++t) {
    const int ky = t / 3, kx = t % 3;
#pragma unroll
    for (int c = 0; c < NC; ++c) {
      short8_t B[NF];
#pragma unroll
      for (int n = 0; n < NF; ++n)
        B[n] = *reinterpret_cast<const short8_t*>(
            wb + (size_t)(((t * NC + c) * NF + n) * 64 + lane) * 8);
#pragma unroll
      for (int m = 0; m < 4; ++m) {
        short8_t A = *reinterpret_cast<const short8_t*>(
            ip + rowoff[m + ky] + aoff[kx] + c * 32);
#pragma unroll
        for (int n = 0; n < NF; ++n)
          acc[m][n] = __builtin_amdgcn_mfma_f32_16x16x32_bf16(A, B[n], acc[m][n], 0, 0, 0);
      }
    }
  }
  // epilogue: relu + NHWC bf16 store. D: row(pixel x) = (lane>>4)*4+r, col(oc) = lane&15
#pragma unroll
  for (int m = 0; m < 4; ++m) {
    int yy = y + m;
    if (yy < HO) {
#pragma unroll
      for (int r = 0; r < 4; ++r) {
        int xx = x0 + (lane >> 4) * 4 + r;
        if (xx < HO) {
#pragma unroll
          for (int n = 0; n < NF; ++n) {
            float v = acc[m][n][r];
            v = v > 0.0f ? v : 0.0f;
            op[((size_t)yy * HO + xx) * COUT + n * 16 + (lane & 15)] = __float2bfloat16(v);
          }
        }
      }
    }
  }
}

// ---------------- conv4: 3x3 32->16 MFMA + sigmoid + pixel_shuffle(r=4) ----------------
__global__ __launch_bounds__(256) void conv4_mfma(
    const __hip_bfloat16* __restrict__ in, float* __restrict__ out,
    const __hip_bfloat16* __restrict__ wb, const float* __restrict__ bias, int bBase) {
  constexpr int CIN = 32, HIN = HO3, HO = HO4;
  const int zb = blockIdx.z;
  const __hip_bfloat16* ip = in + (size_t)zb * HIN * HIN * CIN;
  const int lane = threadIdx.x & 63;
  const int wave = threadIdx.x >> 6;
  const int x0 = blockIdx.x * 16;
  const int y = blockIdx.y * 16 + wave * 4;

  int aoff[3];
#pragma unroll
  for (int kx = 0; kx < 3; ++kx) {
    int px = x0 + (lane & 15) + kx;
    px = px < HIN - 1 ? px : HIN - 1;
    aoff[kx] = px * CIN + (lane >> 4) * 8;
  }
  int rowoff[6];
#pragma unroll
  for (int r = 0; r < 6; ++r) {
    int yy = y + r; yy = yy < HIN - 1 ? yy : HIN - 1;
    rowoff[r] = yy * (HIN * CIN);
  }
  float bv = bias[lane & 15];
  float4_t acc[4];
#pragma unroll
  for (int m = 0; m < 4; ++m) acc[m] = {bv, bv, bv, bv};

#pragma unroll
  for (int t = 0; t < 9; ++t) {
    const int ky = t / 3, kx = t % 3;
    short8_t B = *reinterpret_cast<const short8_t*>(wb + (size_t)(t * 64 + lane) * 8);
#pragma unroll
    for (int m = 0; m < 4; ++m) {
      short8_t A = *reinterpret_cast<const short8_t*>(ip + rowoff[m + ky] + aoff[kx]);
      acc[m] = __builtin_amdgcn_mfma_f32_16x16x32_bf16(A, B, acc[m], 0, 0, 0);
    }
  }
  // sigmoid + pixel_shuffle: oc = lane&15 -> (i,j) = (oc>>2, oc&3)
  float* ob = out + (size_t)(bBase + zb) * 1024 * 1024;
  const int oc = lane & 15;
#pragma unroll
  for (int m = 0; m < 4; ++m) {
    int yy = y + m;
#pragma unroll
    for (int r = 0; r < 4; ++r) {
      int xx = x0 + (lane >> 4) * 4 + r;
      float v = 1.0f / (1.0f + expf(-acc[m][r]));
      ob[(size_t)(yy * 4 + (oc >> 2)) * 1024 + xx * 4 + (oc & 3)] = v;
    }
  }
}

extern "C" void kernel_launch(void* const* d_in, const int* in_sizes, int n_in,
                              void* d_out, int out_size, void* d_ws, size_t ws_size,
                              hipStream_t stream) {
  const float* x  = (const float*)d_in[0];
  const float* W1 = (const float*)d_in[1];
  const float* b1 = (const float*)d_in[2];
  const float* W2 = (const float*)d_in[3];
  const float* b2 = (const float*)d_in[4];
  const float* W3 = (const float*)d_in[5];
  const float* b3 = (const float*)d_in[6];
  const float* W4 = (const float*)d_in[7];
  const float* b4 = (const float*)d_in[8];
  float* out = (float*)d_out;

  // repacked weights at workspace start (64.5 KB, pad to 64 KiB)
  __hip_bfloat16* wr2 = (__hip_bfloat16*)d_ws;   // 18432 elems
  __hip_bfloat16* wr3 = wr2 + 18432;             // 9216
  __hip_bfloat16* wr4 = wr3 + 9216;              // 4608
  char* base = (char*)d_ws + 65536;

  const size_t xp_sz = (size_t)WPD * WPD * sizeof(float);              // 283024
  const size_t h1_sz = (size_t)HO1 * HO1 * 64 * sizeof(__hip_bfloat16); // 8786432
  const size_t h2_sz = (size_t)HO2 * HO2 * 32 * sizeof(__hip_bfloat16); // 4326400
  const size_t h3_sz = (size_t)HO3 * HO3 * 32 * sizeof(__hip_bfloat16); // 4259328
  const size_t per_b = xp_sz + h1_sz + h2_sz + h3_sz;

  int g = (int)((ws_size - 65536) / per_b);
  if (g > 16) g = 16;
  if (g < 1) g = 1;

  float* xp = (float*)base;
  __hip_bfloat16* h1 = (__hip_bfloat16*)(base + (size_t)g * xp_sz);
  __hip_bfloat16* h2 = (__hip_bfloat16*)((char*)h1 + (size_t)g * h1_sz);
  __hip_bfloat16* h3 = (__hip_bfloat16*)((char*)h2 + (size_t)g * h2_sz);

  repack_w<<<72, 256, 0, stream>>>(W2, wr2, 64, 32);
  repack_w<<<36, 256, 0, stream>>>(W3, wr3, 32, 32);
  repack_w<<<18, 256, 0, stream>>>(W4, wr4, 32, 16);

  for (int bBase = 0; bBase < 16; bBase += g) {
    int gc = min(g, 16 - bBase);
    size_t tot = (size_t)gc * WPD * WPD;
    int fillBlocks = (int)min((tot + 255) / 256, (size_t)2048);
    pad_fill_kernel<<<fillBlocks, 256, 0, stream>>>(x, xp, bBase, gc);
    extrap_kernel<<<gc, 256, 0, stream>>>(xp);
    conv1_kernel<<<dim3(17, 17, gc), 256, 0, stream>>>(xp, h1, W1, b1);
    conv3x3_mfma<64, 32, HO1><<<dim3(17, 17, gc), 256, 0, stream>>>(h1, h2, wr2, b2);
    conv3x3_mfma<32, 32, HO2><<<dim3(17, 17, gc), 256, 0, stream>>>(h2, h3, wr3, b3);
    conv4_mfma<<<dim3(16, 16, gc), 256, 0, stream>>>(h3, out, wr4, b4, bBase);
  }
}

// Round 3
// 341.949 us; speedup vs baseline: 4.7253x; 1.1686x over previous
//
#include <hip/hip_runtime.h>
#include <hip/hip_bf16.h>
#include <math.h>

// Geometry
#define WPD 266   // padded H=W
#define HO1 262   // after 5x5
#define HO2 260
#define HO3 258
#define HO4 256

typedef __attribute__((ext_vector_type(8))) short short8_t;
typedef __attribute__((ext_vector_type(4))) float float4_t;

__device__ inline void gld16(const void* g, void* l) {
  __builtin_amdgcn_global_load_lds(
      (const __attribute__((address_space(1))) void*)g,
      (__attribute__((address_space(3))) void*)l, 16, 0, 0);
}

// ---------------- pad fill: xp = pad(x, 5, value=0.5) ----------------
__global__ void pad_fill_kernel(const float* __restrict__ x, float* __restrict__ xp,
                                int bBase, int gc) {
  size_t total = (size_t)gc * WPD * WPD;
  for (size_t idx = (size_t)blockIdx.x * blockDim.x + threadIdx.x; idx < total;
       idx += (size_t)gridDim.x * blockDim.x) {
    size_t zb = idx / (WPD * WPD);
    int rem = (int)(idx % (WPD * WPD));
    int y = rem / WPD, xx = rem % WPD;
    float v = 0.5f;
    if (y >= 5 && y < 261 && xx >= 5 && xx < 261)
      v = x[((size_t)(bBase + zb) * 256 + (y - 5)) * 256 + (xx - 5)];
    xp[idx] = v;
  }
}

// ---------------- border extrapolation (sequential rings i=5..1) ----------------
__global__ void extrap_kernel(float* __restrict__ xp) {
  const int W = WPD, H = WPD;
  float* p = xp + (size_t)blockIdx.x * W * W;
  for (int i = 5; i >= 1; --i) {
    int ip = i + 1, im = i - 1;
    int L = W - 2 * ip;
    for (int t = threadIdx.x; t < 4 * L; t += blockDim.x) {
      int e = t / L, j = t % L;
      float a;
      if (e == 0) {
        a = (p[i * W + i + j] + p[i * W + i + j + 1] + p[i * W + i + j + 2]) / 3.0f;
        p[im * W + ip + j] = a > 0.3f ? 1.0f : a;
      } else if (e == 1) {
        const float* r = p + (H - ip) * W;
        a = (r[i + j] + r[i + j + 1] + r[i + j + 2]) / 3.0f;
        p[(H - i) * W + ip + j] = a > 0.3f ? 1.0f : a;
      } else if (e == 2) {
        a = (p[(i + j) * W + i] + p[(i + j + 1) * W + i] + p[(i + j + 2) * W + i]) / 3.0f;
        p[(ip + j) * W + im] = a > 0.3f ? 1.0f : a;
      } else {
        a = (p[(i + j) * W + (W - ip)] + p[(i + j + 1) * W + (W - ip)] +
             p[(i + j + 2) * W + (W - ip)]) / 3.0f;
        p[(ip + j) * W + (W - i)] = a > 0.3f ? 1.0f : a;
      }
    }
    __syncthreads();
    if (threadIdx.x < 4) {
      int c = threadIdx.x;
      int cx, cy, nx, ny;
      if (c == 0)      { cx = im;    cy = im;    nx = 1;  ny = 1;  }
      else if (c == 1) { cx = W - i; cy = im;    nx = -1; ny = 1;  }
      else if (c == 2) { cx = W - i; cy = H - i; nx = -1; ny = -1; }
      else             { cx = im;    cy = H - i; nx = 1;  ny = -1; }
      int cxp = cx + nx, cyp = cy + ny;
      p[cy * W + cxp] = (p[cyp * W + cxp] + p[cy * W + cx + 2 * nx]) * 0.5f;
      p[cyp * W + cx] = (p[cyp * W + cxp] + p[(cy + 2 * ny) * W + cx]) * 0.5f;
      p[cy * W + cx]  = (p[cy * W + cxp] + p[cyp * W + cx]) * 0.5f;
    }
    __syncthreads();
  }
}

// ---------------- conv1: 5x5, 1 -> 64, relu, f32 in -> bf16 NHWC out ----------------
__global__ __launch_bounds__(256) void conv1_kernel(
    const float* __restrict__ xp, __hip_bfloat16* __restrict__ h1,
    const float* __restrict__ W1, const float* __restrict__ b1) {
  const int HIN = WPD, HO = HO1;
  int zb = blockIdx.z;
  const float* p = xp + (size_t)zb * HIN * HIN;
  int tx = threadIdx.x & 15, ty = threadIdx.x >> 4;
  int x0 = blockIdx.x * 16, y0 = blockIdx.y * 16;
  __shared__ float tile[20][20];
  for (int idx = threadIdx.x; idx < 20 * 20; idx += 256) {
    int r = idx / 20, c = idx % 20;
    int yy = min(y0 + r, HIN - 1), xx = min(x0 + c, HIN - 1);
    tile[r][c] = p[yy * HIN + xx];
  }
  __syncthreads();
  float v[25];
#pragma unroll
  for (int ky = 0; ky < 5; ++ky)
#pragma unroll
    for (int kx = 0; kx < 5; ++kx) v[ky * 5 + kx] = tile[ty + ky][tx + kx];
  int ox = x0 + tx, oy = y0 + ty;
  bool valid = (ox < HO) && (oy < HO);
  __hip_bfloat16* outp = h1 + (size_t)zb * HO * HO * 64;
  size_t obase = ((size_t)oy * HO + ox) * 64;
#pragma unroll 1
  for (int oc0 = 0; oc0 < 64; oc0 += 16) {
    float acc[16];
#pragma unroll
    for (int o = 0; o < 16; ++o) acc[o] = b1[oc0 + o];
#pragma unroll
    for (int o = 0; o < 16; ++o) {
      const float* wp = W1 + (size_t)(oc0 + o) * 25;  // uniform -> s_load
#pragma unroll
      for (int k = 0; k < 25; ++k) acc[o] = fmaf(wp[k], v[k], acc[o]);
    }
    if (valid) {
      short8_t pk0, pk1;
#pragma unroll
      for (int o = 0; o < 8; ++o) {
        float r = acc[o] > 0.0f ? acc[o] : 0.0f;
        __hip_bfloat16 h = __float2bfloat16(r);
        pk0[o] = *reinterpret_cast<short*>(&h);
      }
#pragma unroll
      for (int o = 0; o < 8; ++o) {
        float r = acc[8 + o] > 0.0f ? acc[8 + o] : 0.0f;
        __hip_bfloat16 h = __float2bfloat16(r);
        pk1[o] = *reinterpret_cast<short*>(&h);
      }
      *reinterpret_cast<short8_t*>(outp + obase + oc0) = pk0;
      *reinterpret_cast<short8_t*>(outp + obase + oc0 + 8) = pk1;
    }
  }
}

// ---------------- weight repack for MFMA B-fragments ----------------
// Wr[t][c][n][lane][j] = bf16(W[oc = n*16 + (lane&15)][ic = c*32 + (lane>>4)*8 + j][t])
__global__ void repack_w(const float* __restrict__ W, __hip_bfloat16* __restrict__ Wr,
                         int CIN, int COUT) {
  int NC = CIN / 32, NF = COUT / 16;
  int total = 9 * NC * NF * 512;
  for (int idx = blockIdx.x * blockDim.x + threadIdx.x; idx < total;
       idx += gridDim.x * blockDim.x) {
    int j = idx & 7, l = (idx >> 3) & 63;
    int rest = idx >> 9;
    int n = rest % NF; rest /= NF;
    int c = rest % NC; int t = rest / NC;
    int oc = n * 16 + (l & 15);
    int ic = c * 32 + (l >> 4) * 8 + j;
    Wr[idx] = __float2bfloat16(W[((size_t)oc * CIN + ic) * 9 + t]);
  }
}

// swizzle of the channel-block index by tile-local x (involution, bank-spreading)
template <int CBC>
__device__ inline int swz(int x) {
  if constexpr (CBC == 8) return x & 7;
  else return (x & 3) ^ ((x >> 2) & 3);
}

// ---------------- 3x3 conv via MFMA implicit GEMM + LDS-staged A ----------------
// Block: 16x16 spatial outputs x COUT channels; 4 waves x 4 output rows each.
// Input tile 18x18xCIN staged once via global_load_lds (linear LDS dest,
// swizzle applied on the global SOURCE address; reads apply the same XOR).
template <int CIN, int COUT, int HIN>
__global__ __launch_bounds__(256) void conv3x3_mfma(
    const __hip_bfloat16* __restrict__ in, __hip_bfloat16* __restrict__ out,
    const __hip_bfloat16* __restrict__ wb, const float* __restrict__ bias) {
  constexpr int HO = HIN - 2;
  constexpr int NC = CIN / 32;
  constexpr int NF = COUT / 16;
  constexpr int CBC = CIN / 8;             // 16B chunks per pixel
  constexpr int SH = (CBC == 8) ? 3 : 2;
  constexpr int TX = 18;
  constexpr int SLOTS = 18 * 18 * CBC;
  constexpr int ITERS = (SLOTS + 255) / 256;
  constexpr int ROWSTRIDE = TX * CBC * 16; // bytes per tile row
  __shared__ char lds[ITERS * 256 * 16];

  const int zb = blockIdx.z;
  const __hip_bfloat16* ip = in + (size_t)zb * HIN * HIN * CIN;
  __hip_bfloat16* op = out + (size_t)zb * HO * HO * COUT;
  const int lane = threadIdx.x & 63;
  const int wave = threadIdx.x >> 6;
  const int x0 = blockIdx.x * 16;
  const int y0 = blockIdx.y * 16;

  // ---- stage input tile ----
#pragma unroll
  for (int i = 0; i < ITERS; ++i) {
    int sbase = i * 256 + wave * 64;       // wave-uniform
    int slot = sbase + lane;
    slot = slot < SLOTS ? slot : SLOTS - 1;
    int pix = slot >> SH, scb = slot & (CBC - 1);
    int y = pix / TX, x = pix - y * TX;
    int cb = scb ^ swz<CBC>(x);
    int gy = min(y0 + y, HIN - 1), gx = min(x0 + x, HIN - 1);
    const __hip_bfloat16* src = ip + ((size_t)gy * HIN + gx) * CIN + cb * 8;
    gld16(src, lds + (size_t)sbase * 16);
  }
  __syncthreads();

  // ---- A-fragment LDS byte addresses (per kx, per 32-ch group) ----
  int abase[3][NC];
#pragma unroll
  for (int kx = 0; kx < 3; ++kx) {
#pragma unroll
    for (int c = 0; c < NC; ++c) {
      int x = (lane & 15) + kx;
      int cb = c * 4 + (lane >> 4);
      int slot = cb ^ swz<CBC>(x);
      abase[kx][c] = (x * CBC + slot) * 16 + wave * 4 * ROWSTRIDE;
    }
  }

  float bv[NF];
#pragma unroll
  for (int n = 0; n < NF; ++n) bv[n] = bias[n * 16 + (lane & 15)];
  float4_t acc[4][NF];
#pragma unroll
  for (int m = 0; m < 4; ++m)
#pragma unroll
    for (int n = 0; n < NF; ++n) acc[m][n] = {bv[n], bv[n], bv[n], bv[n]};

#pragma unroll
  for (int t = 0; t < 9; ++t) {
    const int ky = t / 3, kx = t % 3;
#pragma unroll
    for (int c = 0; c < NC; ++c) {
      short8_t B[NF];
#pragma unroll
      for (int n = 0; n < NF; ++n)
        B[n] = *reinterpret_cast<const short8_t*>(
            wb + (size_t)(((t * NC + c) * NF + n) * 64 + lane) * 8);
#pragma unroll
      for (int m = 0; m < 4; ++m) {
        short8_t A = *reinterpret_cast<const short8_t*>(
            lds + abase[kx][c] + (m + ky) * ROWSTRIDE);
#pragma unroll
        for (int n = 0; n < NF; ++n)
          acc[m][n] = __builtin_amdgcn_mfma_f32_16x16x32_bf16(A, B[n], acc[m][n], 0, 0, 0);
      }
    }
  }
  // epilogue: relu + NHWC bf16 store
#pragma unroll
  for (int m = 0; m < 4; ++m) {
    int yy = y0 + wave * 4 + m;
    if (yy < HO) {
#pragma unroll
      for (int r = 0; r < 4; ++r) {
        int xx = x0 + (lane >> 4) * 4 + r;
        if (xx < HO) {
#pragma unroll
          for (int n = 0; n < NF; ++n) {
            float v = acc[m][n][r];
            v = v > 0.0f ? v : 0.0f;
            op[((size_t)yy * HO + xx) * COUT + n * 16 + (lane & 15)] = __float2bfloat16(v);
          }
        }
      }
    }
  }
}

// ---------------- conv4: 3x3 32->16 MFMA + sigmoid + pixel_shuffle(r=4) ----------------
__global__ __launch_bounds__(256) void conv4_mfma(
    const __hip_bfloat16* __restrict__ in, float* __restrict__ out,
    const __hip_bfloat16* __restrict__ wb, const float* __restrict__ bias, int bBase) {
  constexpr int CIN = 32, HIN = HO3;
  constexpr int CBC = 4, SH = 2, TX = 18;
  constexpr int SLOTS = 18 * 18 * CBC;
  constexpr int ITERS = (SLOTS + 255) / 256;
  constexpr int ROWSTRIDE = TX * CBC * 16;
  __shared__ char lds[ITERS * 256 * 16];

  const int zb = blockIdx.z;
  const __hip_bfloat16* ip = in + (size_t)zb * HIN * HIN * CIN;
  const int lane = threadIdx.x & 63;
  const int wave = threadIdx.x >> 6;
  const int x0 = blockIdx.x * 16;
  const int y0 = blockIdx.y * 16;

#pragma unroll
  for (int i = 0; i < ITERS; ++i) {
    int sbase = i * 256 + wave * 64;
    int slot = sbase + lane;
    slot = slot < SLOTS ? slot : SLOTS - 1;
    int pix = slot >> SH, scb = slot & (CBC - 1);
    int y = pix / TX, x = pix - y * TX;
    int cb = scb ^ swz<CBC>(x);
    int gy = min(y0 + y, HIN - 1), gx = min(x0 + x, HIN - 1);
    const __hip_bfloat16* src = ip + ((size_t)gy * HIN + gx) * CIN + cb * 8;
    gld16(src, lds + (size_t)sbase * 16);
  }
  __syncthreads();

  int abase[3];
#pragma unroll
  for (int kx = 0; kx < 3; ++kx) {
    int x = (lane & 15) + kx;
    int cb = lane >> 4;
    int slot = cb ^ swz<CBC>(x);
    abase[kx] = (x * CBC + slot) * 16 + wave * 4 * ROWSTRIDE;
  }

  float bv = bias[lane & 15];
  float4_t acc[4];
#pragma unroll
  for (int m = 0; m < 4; ++m) acc[m] = {bv, bv, bv, bv};

#pragma unroll
  for (int t = 0; t < 9; ++t) {
    const int ky = t / 3, kx = t % 3;
    short8_t B = *reinterpret_cast<const short8_t*>(wb + (size_t)(t * 64 + lane) * 8);
#pragma unroll
    for (int m = 0; m < 4; ++m) {
      short8_t A = *reinterpret_cast<const short8_t*>(
          lds + abase[kx] + (m + ky) * ROWSTRIDE);
      acc[m] = __builtin_amdgcn_mfma_f32_16x16x32_bf16(A, B, acc[m], 0, 0, 0);
    }
  }
  // sigmoid + pixel_shuffle: oc = lane&15 -> (i,j) = (oc>>2, oc&3)
  float* ob = out + (size_t)(bBase + zb) * 1024 * 1024;
  const int oc = lane & 15;
#pragma unroll
  for (int m = 0; m < 4; ++m) {
    int yy = y0 + wave * 4 + m;
#pragma unroll
    for (int r = 0; r < 4; ++r) {
      int xx = x0 + (lane >> 4) * 4 + r;
      float v = 1.0f / (1.0f + expf(-acc[m][r]));
      ob[(size_t)(yy * 4 + (oc >> 2)) * 1024 + xx * 4 + (oc & 3)] = v;
    }
  }
}

extern "C" void kernel_launch(void* const* d_in, const int* in_sizes, int n_in,
                              void* d_out, int out_size, void* d_ws, size_t ws_size,
                              hipStream_t stream) {
  const float* x  = (const float*)d_in[0];
  const float* W1 = (const float*)d_in[1];
  const float* b1 = (const float*)d_in[2];
  const float* W2 = (const float*)d_in[3];
  const float* b2 = (const float*)d_in[4];
  const float* W3 = (const float*)d_in[5];
  const float* b3 = (const float*)d_in[6];
  const float* W4 = (const float*)d_in[7];
  const float* b4 = (const float*)d_in[8];
  float* out = (float*)d_out;

  __hip_bfloat16* wr2 = (__hip_bfloat16*)d_ws;   // 18432 elems
  __hip_bfloat16* wr3 = wr2 + 18432;             // 9216
  __hip_bfloat16* wr4 = wr3 + 9216;              // 4608
  char* base = (char*)d_ws + 65536;

  const size_t xp_sz = (size_t)WPD * WPD * sizeof(float);
  const size_t h1_sz = (size_t)HO1 * HO1 * 64 * sizeof(__hip_bfloat16);
  const size_t h2_sz = (size_t)HO2 * HO2 * 32 * sizeof(__hip_bfloat16);
  const size_t h3_sz = (size_t)HO3 * HO3 * 32 * sizeof(__hip_bfloat16);
  const size_t per_b = xp_sz + h1_sz + h2_sz + h3_sz;

  int g = (int)((ws_size - 65536) / per_b);
  if (g > 16) g = 16;
  if (g < 1) g = 1;

  float* xp = (float*)base;
  __hip_bfloat16* h1 = (__hip_bfloat16*)(base + (size_t)g * xp_sz);
  __hip_bfloat16* h2 = (__hip_bfloat16*)((char*)h1 + (size_t)g * h1_sz);
  __hip_bfloat16* h3 = (__hip_bfloat16*)((char*)h2 + (size_t)g * h2_sz);

  repack_w<<<72, 256, 0, stream>>>(W2, wr2, 64, 32);
  repack_w<<<36, 256, 0, stream>>>(W3, wr3, 32, 32);
  repack_w<<<18, 256, 0, stream>>>(W4, wr4, 32, 16);

  for (int bBase = 0; bBase < 16; bBase += g) {
    int gc = min(g, 16 - bBase);
    size_t tot = (size_t)gc * WPD * WPD;
    int fillBlocks = (int)min((tot + 255) / 256, (size_t)2048);
    pad_fill_kernel<<<fillBlocks, 256, 0, stream>>>(x, xp, bBase, gc);
    extrap_kernel<<<gc, 256, 0, stream>>>(xp);
    conv1_kernel<<<dim3(17, 17, gc), 256, 0, stream>>>(xp, h1, W1, b1);
    conv3x3_mfma<64, 32, HO1><<<dim3(17, 17, gc), 256, 0, stream>>>(h1, h2, wr2, b2);
    conv3x3_mfma<32, 32, HO2><<<dim3(17, 17, gc), 256, 0, stream>>>(h2, h3, wr3, b3);
    conv4_mfma<<<dim3(16, 16, gc), 256, 0, stream>>>(h3, out, wr4, b4, bBase);
  }
}

// Round 4
// 341.398 us; speedup vs baseline: 4.7329x; 1.0016x over previous
//
#include <hip/hip_runtime.h>
#include <hip/hip_bf16.h>
#include <math.h>

// Geometry
#define WPD 266   // padded H=W
#define HO1 262   // after 5x5
#define HO2 260
#define HO3 258
#define HO4 256

typedef __attribute__((ext_vector_type(8))) short short8_t;
typedef __attribute__((ext_vector_type(4))) float float4_t;

__device__ inline void gld16(const void* g, void* l) {
  __builtin_amdgcn_global_load_lds(
      (const __attribute__((address_space(1))) void*)g,
      (__attribute__((address_space(3))) void*)l, 16, 0, 0);
}

// ---------------- pad fill: xp = pad(x, 5, value=0.5) ----------------
__global__ void pad_fill_kernel(const float* __restrict__ x, float* __restrict__ xp,
                                int bBase, int gc) {
  size_t total = (size_t)gc * WPD * WPD;
  for (size_t idx = (size_t)blockIdx.x * blockDim.x + threadIdx.x; idx < total;
       idx += (size_t)gridDim.x * blockDim.x) {
    size_t zb = idx / (WPD * WPD);
    int rem = (int)(idx % (WPD * WPD));
    int y = rem / WPD, xx = rem % WPD;
    float v = 0.5f;
    if (y >= 5 && y < 261 && xx >= 5 && xx < 261)
      v = x[((size_t)(bBase + zb) * 256 + (y - 5)) * 256 + (xx - 5)];
    xp[idx] = v;
  }
}

// ---------------- border extrapolation (sequential rings i=5..1) ----------------
__global__ void extrap_kernel(float* __restrict__ xp) {
  const int W = WPD, H = WPD;
  float* p = xp + (size_t)blockIdx.x * W * W;
  for (int i = 5; i >= 1; --i) {
    int ip = i + 1, im = i - 1;
    int L = W - 2 * ip;
    for (int t = threadIdx.x; t < 4 * L; t += blockDim.x) {
      int e = t / L, j = t % L;
      float a;
      if (e == 0) {
        a = (p[i * W + i + j] + p[i * W + i + j + 1] + p[i * W + i + j + 2]) / 3.0f;
        p[im * W + ip + j] = a > 0.3f ? 1.0f : a;
      } else if (e == 1) {
        const float* r = p + (H - ip) * W;
        a = (r[i + j] + r[i + j + 1] + r[i + j + 2]) / 3.0f;
        p[(H - i) * W + ip + j] = a > 0.3f ? 1.0f : a;
      } else if (e == 2) {
        a = (p[(i + j) * W + i] + p[(i + j + 1) * W + i] + p[(i + j + 2) * W + i]) / 3.0f;
        p[(ip + j) * W + im] = a > 0.3f ? 1.0f : a;
      } else {
        a = (p[(i + j) * W + (W - ip)] + p[(i + j + 1) * W + (W - ip)] +
             p[(i + j + 2) * W + (W - ip)]) / 3.0f;
        p[(ip + j) * W + (W - i)] = a > 0.3f ? 1.0f : a;
      }
    }
    __syncthreads();
    if (threadIdx.x < 4) {
      int c = threadIdx.x;
      int cx, cy, nx, ny;
      if (c == 0)      { cx = im;    cy = im;    nx = 1;  ny = 1;  }
      else if (c == 1) { cx = W - i; cy = im;    nx = -1; ny = 1;  }
      else if (c == 2) { cx = W - i; cy = H - i; nx = -1; ny = -1; }
      else             { cx = im;    cy = H - i; nx = 1;  ny = -1; }
      int cxp = cx + nx, cyp = cy + ny;
      p[cy * W + cxp] = (p[cyp * W + cxp] + p[cy * W + cx + 2 * nx]) * 0.5f;
      p[cyp * W + cx] = (p[cyp * W + cxp] + p[(cy + 2 * ny) * W + cx]) * 0.5f;
      p[cy * W + cx]  = (p[cy * W + cxp] + p[cyp * W + cx]) * 0.5f;
    }
    __syncthreads();
  }
}

// ---------------- conv1: 5x5, 1 -> 64, relu, f32 in -> bf16 NHWC out ----------------
// All 64 oc accumulated in registers; each pixel's full 128B written in one
// contiguous 8x16B burst (avoids partial-line write inflation seen in R3).
__global__ __launch_bounds__(256) void conv1_kernel(
    const float* __restrict__ xp, __hip_bfloat16* __restrict__ h1,
    const float* __restrict__ W1, const float* __restrict__ b1) {
  const int HIN = WPD, HO = HO1;
  int zb = blockIdx.z;
  const float* p = xp + (size_t)zb * HIN * HIN;
  int tx = threadIdx.x & 15, ty = threadIdx.x >> 4;
  int x0 = blockIdx.x * 16, y0 = blockIdx.y * 16;
  __shared__ float tile[20][20];
  for (int idx = threadIdx.x; idx < 20 * 20; idx += 256) {
    int r = idx / 20, c = idx % 20;
    int yy = min(y0 + r, HIN - 1), xx = min(x0 + c, HIN - 1);
    tile[r][c] = p[yy * HIN + xx];
  }
  __syncthreads();
  float v[25];
#pragma unroll
  for (int ky = 0; ky < 5; ++ky)
#pragma unroll
    for (int kx = 0; kx < 5; ++kx) v[ky * 5 + kx] = tile[ty + ky][tx + kx];
  int ox = x0 + tx, oy = y0 + ty;
  bool valid = (ox < HO) && (oy < HO);
  __hip_bfloat16* outp = h1 + (size_t)zb * HO * HO * 64;
  size_t obase = ((size_t)oy * HO + ox) * 64;

  float acc[64];
#pragma unroll
  for (int o = 0; o < 64; ++o) acc[o] = b1[o];           // uniform -> s_load
#pragma unroll
  for (int o = 0; o < 64; ++o) {
    const float* wp = W1 + (size_t)o * 25;               // uniform -> s_load
#pragma unroll
    for (int k = 0; k < 25; ++k) acc[o] = fmaf(wp[k], v[k], acc[o]);
  }
  if (valid) {
#pragma unroll
    for (int pp = 0; pp < 8; ++pp) {
      short8_t pk;
#pragma unroll
      for (int o = 0; o < 8; ++o) {
        float r = acc[pp * 8 + o] > 0.0f ? acc[pp * 8 + o] : 0.0f;
        __hip_bfloat16 h = __float2bfloat16(r);
        pk[o] = *reinterpret_cast<short*>(&h);
      }
      *reinterpret_cast<short8_t*>(outp + obase + pp * 8) = pk;
    }
  }
}

// ---------------- weight repack for MFMA B-fragments ----------------
// Wr[t][c][n][lane][j] = bf16(W[oc = n*16 + (lane&15)][ic = c*32 + (lane>>4)*8 + j][t])
__global__ void repack_w(const float* __restrict__ W, __hip_bfloat16* __restrict__ Wr,
                         int CIN, int COUT) {
  int NC = CIN / 32, NF = COUT / 16;
  int total = 9 * NC * NF * 512;
  for (int idx = blockIdx.x * blockDim.x + threadIdx.x; idx < total;
       idx += gridDim.x * blockDim.x) {
    int j = idx & 7, l = (idx >> 3) & 63;
    int rest = idx >> 9;
    int n = rest % NF; rest /= NF;
    int c = rest % NC; int t = rest / NC;
    int oc = n * 16 + (l & 15);
    int ic = c * 32 + (l >> 4) * 8 + j;
    Wr[idx] = __float2bfloat16(W[((size_t)oc * CIN + ic) * 9 + t]);
  }
}

// swizzle of the channel-block index by tile-local x (involution, bank-spreading)
template <int CBC>
__device__ inline int swz(int x) {
  if constexpr (CBC == 8) return x & 7;
  else return (x & 3) ^ ((x >> 2) & 3);
}

// ---------------- 3x3 conv via MFMA implicit GEMM + LDS-staged A ----------------
template <int CIN, int COUT, int HIN>
__global__ __launch_bounds__(256) void conv3x3_mfma(
    const __hip_bfloat16* __restrict__ in, __hip_bfloat16* __restrict__ out,
    const __hip_bfloat16* __restrict__ wb, const float* __restrict__ bias) {
  constexpr int HO = HIN - 2;
  constexpr int NC = CIN / 32;
  constexpr int NF = COUT / 16;
  constexpr int CBC = CIN / 8;             // 16B chunks per pixel
  constexpr int SH = (CBC == 8) ? 3 : 2;
  constexpr int TX = 18;
  constexpr int SLOTS = 18 * 18 * CBC;
  constexpr int ITERS = (SLOTS + 255) / 256;
  constexpr int ROWSTRIDE = TX * CBC * 16; // bytes per tile row
  __shared__ char lds[ITERS * 256 * 16];

  const int zb = blockIdx.z;
  const __hip_bfloat16* ip = in + (size_t)zb * HIN * HIN * CIN;
  __hip_bfloat16* op = out + (size_t)zb * HO * HO * COUT;
  const int lane = threadIdx.x & 63;
  const int wave = threadIdx.x >> 6;
  const int x0 = blockIdx.x * 16;
  const int y0 = blockIdx.y * 16;

  // ---- stage input tile ----
#pragma unroll
  for (int i = 0; i < ITERS; ++i) {
    int sbase = i * 256 + wave * 64;       // wave-uniform
    int slot = sbase + lane;
    slot = slot < SLOTS ? slot : SLOTS - 1;
    int pix = slot >> SH, scb = slot & (CBC - 1);
    int y = pix / TX, x = pix - y * TX;
    int cb = scb ^ swz<CBC>(x);
    int gy = min(y0 + y, HIN - 1), gx = min(x0 + x, HIN - 1);
    const __hip_bfloat16* src = ip + ((size_t)gy * HIN + gx) * CIN + cb * 8;
    gld16(src, lds + (size_t)sbase * 16);
  }
  __syncthreads();

  // ---- A-fragment LDS byte addresses (per kx, per 32-ch group) ----
  int abase[3][NC];
#pragma unroll
  for (int kx = 0; kx < 3; ++kx) {
#pragma unroll
    for (int c = 0; c < NC; ++c) {
      int x = (lane & 15) + kx;
      int cb = c * 4 + (lane >> 4);
      int slot = cb ^ swz<CBC>(x);
      abase[kx][c] = (x * CBC + slot) * 16 + wave * 4 * ROWSTRIDE;
    }
  }

  float bv[NF];
#pragma unroll
  for (int n = 0; n < NF; ++n) bv[n] = bias[n * 16 + (lane & 15)];
  float4_t acc[4][NF];
#pragma unroll
  for (int m = 0; m < 4; ++m)
#pragma unroll
    for (int n = 0; n < NF; ++n) acc[m][n] = {bv[n], bv[n], bv[n], bv[n]};

#pragma unroll
  for (int t = 0; t < 9; ++t) {
    const int ky = t / 3, kx = t % 3;
#pragma unroll
    for (int c = 0; c < NC; ++c) {
      short8_t B[NF];
#pragma unroll
      for (int n = 0; n < NF; ++n)
        B[n] = *reinterpret_cast<const short8_t*>(
            wb + (size_t)(((t * NC + c) * NF + n) * 64 + lane) * 8);
#pragma unroll
      for (int m = 0; m < 4; ++m) {
        short8_t A = *reinterpret_cast<const short8_t*>(
            lds + abase[kx][c] + (m + ky) * ROWSTRIDE);
#pragma unroll
        for (int n = 0; n < NF; ++n)
          acc[m][n] = __builtin_amdgcn_mfma_f32_16x16x32_bf16(A, B[n], acc[m][n], 0, 0, 0);
      }
    }
  }
  // epilogue: relu + NHWC bf16 store
#pragma unroll
  for (int m = 0; m < 4; ++m) {
    int yy = y0 + wave * 4 + m;
    if (yy < HO) {
#pragma unroll
      for (int r = 0; r < 4; ++r) {
        int xx = x0 + (lane >> 4) * 4 + r;
        if (xx < HO) {
#pragma unroll
          for (int n = 0; n < NF; ++n) {
            float v = acc[m][n][r];
            v = v > 0.0f ? v : 0.0f;
            op[((size_t)yy * HO + xx) * COUT + n * 16 + (lane & 15)] = __float2bfloat16(v);
          }
        }
      }
    }
  }
}

// ---------------- conv4: 3x3 32->16 MFMA + sigmoid + pixel_shuffle(r=4) ----------------
__global__ __launch_bounds__(256) void conv4_mfma(
    const __hip_bfloat16* __restrict__ in, float* __restrict__ out,
    const __hip_bfloat16* __restrict__ wb, const float* __restrict__ bias, int bBase) {
  constexpr int CIN = 32, HIN = HO3;
  constexpr int CBC = 4, SH = 2, TX = 18;
  constexpr int SLOTS = 18 * 18 * CBC;
  constexpr int ITERS = (SLOTS + 255) / 256;
  constexpr int ROWSTRIDE = TX * CBC * 16;
  __shared__ char lds[ITERS * 256 * 16];

  const int zb = blockIdx.z;
  const __hip_bfloat16* ip = in + (size_t)zb * HIN * HIN * CIN;
  const int lane = threadIdx.x & 63;
  const int wave = threadIdx.x >> 6;
  const int x0 = blockIdx.x * 16;
  const int y0 = blockIdx.y * 16;

#pragma unroll
  for (int i = 0; i < ITERS; ++i) {
    int sbase = i * 256 + wave * 64;
    int slot = sbase + lane;
    slot = slot < SLOTS ? slot : SLOTS - 1;
    int pix = slot >> SH, scb = slot & (CBC - 1);
    int y = pix / TX, x = pix - y * TX;
    int cb = scb ^ swz<CBC>(x);
    int gy = min(y0 + y, HIN - 1), gx = min(x0 + x, HIN - 1);
    const __hip_bfloat16* src = ip + ((size_t)gy * HIN + gx) * CIN + cb * 8;
    gld16(src, lds + (size_t)sbase * 16);
  }
  __syncthreads();

  int abase[3];
#pragma unroll
  for (int kx = 0; kx < 3; ++kx) {
    int x = (lane & 15) + kx;
    int cb = lane >> 4;
    int slot = cb ^ swz<CBC>(x);
    abase[kx] = (x * CBC + slot) * 16 + wave * 4 * ROWSTRIDE;
  }

  float bv = bias[lane & 15];
  float4_t acc[4];
#pragma unroll
  for (int m = 0; m < 4; ++m) acc[m] = {bv, bv, bv, bv};

#pragma unroll
  for (int t = 0; t < 9; ++t) {
    const int ky = t / 3, kx = t % 3;
    short8_t B = *reinterpret_cast<const short8_t*>(wb + (size_t)(t * 64 + lane) * 8);
#pragma unroll
    for (int m = 0; m < 4; ++m) {
      short8_t A = *reinterpret_cast<const short8_t*>(
          lds + abase[kx] + (m + ky) * ROWSTRIDE);
      acc[m] = __builtin_amdgcn_mfma_f32_16x16x32_bf16(A, B, acc[m], 0, 0, 0);
    }
  }
  // sigmoid + pixel_shuffle: oc = lane&15 -> (i,j) = (oc>>2, oc&3)
  float* ob = out + (size_t)(bBase + zb) * 1024 * 1024;
  const int oc = lane & 15;
#pragma unroll
  for (int m = 0; m < 4; ++m) {
    int yy = y0 + wave * 4 + m;
#pragma unroll
    for (int r = 0; r < 4; ++r) {
      int xx = x0 + (lane >> 4) * 4 + r;
      float v = 1.0f / (1.0f + expf(-acc[m][r]));
      ob[(size_t)(yy * 4 + (oc >> 2)) * 1024 + xx * 4 + (oc & 3)] = v;
    }
  }
}

extern "C" void kernel_launch(void* const* d_in, const int* in_sizes, int n_in,
                              void* d_out, int out_size, void* d_ws, size_t ws_size,
                              hipStream_t stream) {
  const float* x  = (const float*)d_in[0];
  const float* W1 = (const float*)d_in[1];
  const float* b1 = (const float*)d_in[2];
  const float* W2 = (const float*)d_in[3];
  const float* b2 = (const float*)d_in[4];
  const float* W3 = (const float*)d_in[5];
  const float* b3 = (const float*)d_in[6];
  const float* W4 = (const float*)d_in[7];
  const float* b4 = (const float*)d_in[8];
  float* out = (float*)d_out;

  __hip_bfloat16* wr2 = (__hip_bfloat16*)d_ws;   // 18432 elems
  __hip_bfloat16* wr3 = wr2 + 18432;             // 9216
  __hip_bfloat16* wr4 = wr3 + 9216;              // 4608
  char* base = (char*)d_ws + 65536;

  const size_t xp_sz = (size_t)WPD * WPD * sizeof(float);
  const size_t h1_sz = (size_t)HO1 * HO1 * 64 * sizeof(__hip_bfloat16);
  const size_t h2_sz = (size_t)HO2 * HO2 * 32 * sizeof(__hip_bfloat16);
  const size_t h3_sz = (size_t)HO3 * HO3 * 32 * sizeof(__hip_bfloat16);
  const size_t per_b = xp_sz + h1_sz + h2_sz + h3_sz;

  int g = (int)((ws_size - 65536) / per_b);
  if (g > 16) g = 16;
  if (g < 1) g = 1;

  float* xp = (float*)base;
  __hip_bfloat16* h1 = (__hip_bfloat16*)(base + (size_t)g * xp_sz);
  __hip_bfloat16* h2 = (__hip_bfloat16*)((char*)h1 + (size_t)g * h1_sz);
  __hip_bfloat16* h3 = (__hip_bfloat16*)((char*)h2 + (size_t)g * h2_sz);

  repack_w<<<72, 256, 0, stream>>>(W2, wr2, 64, 32);
  repack_w<<<36, 256, 0, stream>>>(W3, wr3, 32, 32);
  repack_w<<<18, 256, 0, stream>>>(W4, wr4, 32, 16);

  for (int bBase = 0; bBase < 16; bBase += g) {
    int gc = min(g, 16 - bBase);
    size_t tot = (size_t)gc * WPD * WPD;
    int fillBlocks = (int)min((tot + 255) / 256, (size_t)2048);
    pad_fill_kernel<<<fillBlocks, 256, 0, stream>>>(x, xp, bBase, gc);
    extrap_kernel<<<gc, 256, 0, stream>>>(xp);
    conv1_kernel<<<dim3(17, 17, gc), 256, 0, stream>>>(xp, h1, W1, b1);
    conv3x3_mfma<64, 32, HO1><<<dim3(17, 17, gc), 256, 0, stream>>>(h1, h2, wr2, b2);
    conv3x3_mfma<32, 32, HO2><<<dim3(17, 17, gc), 256, 0, stream>>>(h2, h3, wr3, b3);
    conv4_mfma<<<dim3(16, 16, gc), 256, 0, stream>>>(h3, out, wr4, b4, bBase);
  }
}

// Round 5
// 263.521 us; speedup vs baseline: 6.1316x; 1.2955x over previous
//
#include <hip/hip_runtime.h>
#include <hip/hip_bf16.h>
#include <math.h>

// Geometry
#define WPD 266   // padded H=W
#define HO1 262   // after 5x5
#define HO2 260
#define HO3 258
#define HO4 256

typedef __attribute__((ext_vector_type(8))) short short8_t;
typedef __attribute__((ext_vector_type(4))) float float4_t;

__device__ inline void gld16(const void* g, void* l) {
  __builtin_amdgcn_global_load_lds(
      (const __attribute__((address_space(1))) void*)g,
      (__attribute__((address_space(3))) void*)l, 16, 0, 0);
}

// ---------------- pad fill: xp = pad(x, 5, value=0.5) ----------------
__global__ void pad_fill_kernel(const float* __restrict__ x, float* __restrict__ xp,
                                int bBase, int gc) {
  size_t total = (size_t)gc * WPD * WPD;
  for (size_t idx = (size_t)blockIdx.x * blockDim.x + threadIdx.x; idx < total;
       idx += (size_t)gridDim.x * blockDim.x) {
    size_t zb = idx / (WPD * WPD);
    int rem = (int)(idx % (WPD * WPD));
    int y = rem / WPD, xx = rem % WPD;
    float v = 0.5f;
    if (y >= 5 && y < 261 && xx >= 5 && xx < 261)
      v = x[((size_t)(bBase + zb) * 256 + (y - 5)) * 256 + (xx - 5)];
    xp[idx] = v;
  }
}

// ---------------- border extrapolation (sequential rings i=5..1) ----------------
__global__ void extrap_kernel(float* __restrict__ xp) {
  const int W = WPD, H = WPD;
  float* p = xp + (size_t)blockIdx.x * W * W;
  for (int i = 5; i >= 1; --i) {
    int ip = i + 1, im = i - 1;
    int L = W - 2 * ip;
    for (int t = threadIdx.x; t < 4 * L; t += blockDim.x) {
      int e = t / L, j = t % L;
      float a;
      if (e == 0) {
        a = (p[i * W + i + j] + p[i * W + i + j + 1] + p[i * W + i + j + 2]) / 3.0f;
        p[im * W + ip + j] = a > 0.3f ? 1.0f : a;
      } else if (e == 1) {
        const float* r = p + (H - ip) * W;
        a = (r[i + j] + r[i + j + 1] + r[i + j + 2]) / 3.0f;
        p[(H - i) * W + ip + j] = a > 0.3f ? 1.0f : a;
      } else if (e == 2) {
        a = (p[(i + j) * W + i] + p[(i + j + 1) * W + i] + p[(i + j + 2) * W + i]) / 3.0f;
        p[(ip + j) * W + im] = a > 0.3f ? 1.0f : a;
      } else {
        a = (p[(i + j) * W + (W - ip)] + p[(i + j + 1) * W + (W - ip)] +
             p[(i + j + 2) * W + (W - ip)]) / 3.0f;
        p[(ip + j) * W + (W - i)] = a > 0.3f ? 1.0f : a;
      }
    }
    __syncthreads();
    if (threadIdx.x < 4) {
      int c = threadIdx.x;
      int cx, cy, nx, ny;
      if (c == 0)      { cx = im;    cy = im;    nx = 1;  ny = 1;  }
      else if (c == 1) { cx = W - i; cy = im;    nx = -1; ny = 1;  }
      else if (c == 2) { cx = W - i; cy = H - i; nx = -1; ny = -1; }
      else             { cx = im;    cy = H - i; nx = 1;  ny = -1; }
      int cxp = cx + nx, cyp = cy + ny;
      p[cy * W + cxp] = (p[cyp * W + cxp] + p[cy * W + cx + 2 * nx]) * 0.5f;
      p[cyp * W + cx] = (p[cyp * W + cxp] + p[(cy + 2 * ny) * W + cx]) * 0.5f;
      p[cy * W + cx]  = (p[cy * W + cxp] + p[cyp * W + cx]) * 0.5f;
    }
    __syncthreads();
  }
}

// ---------------- conv1 weight repack: Wr[n][lane][j] = W1[oc][tap], tap>=25 -> 0 ----
__global__ void repack_w1(const float* __restrict__ W, __hip_bfloat16* __restrict__ Wr) {
  int idx = blockIdx.x * blockDim.x + threadIdx.x;
  if (idx < 2048) {
    int j = idx & 7, l = (idx >> 3) & 63, n = idx >> 9;
    int oc = n * 16 + (l & 15);
    int tap = (l >> 4) * 8 + j;
    Wr[idx] = __float2bfloat16(tap < 25 ? W[oc * 25 + tap] : 0.0f);
  }
}

// ---------------- conv1: 5x5 1->64 via MFMA (K=25 taps padded to 32) ----------------
// Block: 16x16 output pixels, 4 waves x 4 rows. 20x20 bf16 tile in LDS + 4 zero
// rows (taps 25..31 read zeros under the same +m*row walk). A and B share the
// (lane>>4, j) -> tap map so the K-permutation cancels.
__global__ __launch_bounds__(256) void conv1_mfma(
    const float* __restrict__ xp, __hip_bfloat16* __restrict__ h1,
    const __hip_bfloat16* __restrict__ wb, const float* __restrict__ b1) {
  const int HIN = WPD, HO = HO1;
  const int zb = blockIdx.z;
  const float* p = xp + (size_t)zb * HIN * HIN;
  const int x0 = blockIdx.x * 16, y0 = blockIdx.y * 16;
  const int lane = threadIdx.x & 63;
  const int wave = threadIdx.x >> 6;
  const int lx = lane & 15, kg = lane >> 4;
  const int ly = wave * 4;

  __shared__ short tile[24 * 20];  // rows 0..19 data, 20..23 zeros
  for (int idx = threadIdx.x; idx < 24 * 20; idx += 256) {
    int r = idx / 20, c = idx % 20;
    short v = 0;
    if (r < 20) {
      int yy = min(y0 + r, HIN - 1), xx = min(x0 + c, HIN - 1);
      __hip_bfloat16 h = __float2bfloat16(p[yy * HIN + xx]);
      v = *reinterpret_cast<short*>(&h);
    }
    tile[idx] = v;
  }
  __syncthreads();

  // per-lane A offsets (short-indexed); invalid taps -> zero rows (no m-fold issue:
  // rows 20..23 all zero so +m*20 stays in the zero region)
  int aoff[8];
#pragma unroll
  for (int j = 0; j < 8; ++j) {
    int tap = kg * 8 + j;
    int ky = tap / 5, kx = tap % 5;
    aoff[j] = (tap < 25) ? ((ly + ky) * 20 + kx + lx) : (20 * 20 + lx);
  }

  float bv[4];
#pragma unroll
  for (int n = 0; n < 4; ++n) bv[n] = b1[n * 16 + lx];
  float4_t acc[4][4];
#pragma unroll
  for (int m = 0; m < 4; ++m)
#pragma unroll
    for (int n = 0; n < 4; ++n) acc[m][n] = {bv[n], bv[n], bv[n], bv[n]};

  short8_t B[4];
#pragma unroll
  for (int n = 0; n < 4; ++n)
    B[n] = *reinterpret_cast<const short8_t*>(wb + (size_t)(n * 64 + lane) * 8);

#pragma unroll
  for (int m = 0; m < 4; ++m) {
    short8_t A;
#pragma unroll
    for (int j = 0; j < 8; ++j) A[j] = tile[aoff[j] + m * 20];
#pragma unroll
    for (int n = 0; n < 4; ++n)
      acc[m][n] = __builtin_amdgcn_mfma_f32_16x16x32_bf16(A, B[n], acc[m][n], 0, 0, 0);
  }

  __hip_bfloat16* op = h1 + (size_t)zb * HO * HO * 64;
#pragma unroll
  for (int m = 0; m < 4; ++m) {
    int yy = y0 + ly + m;
    if (yy < HO) {
#pragma unroll
      for (int r = 0; r < 4; ++r) {
        int xx = x0 + kg * 4 + r;
        if (xx < HO) {
#pragma unroll
          for (int n = 0; n < 4; ++n) {
            float v = acc[m][n][r];
            v = v > 0.0f ? v : 0.0f;
            op[((size_t)yy * HO + xx) * 64 + n * 16 + lx] = __float2bfloat16(v);
          }
        }
      }
    }
  }
}

// ---------------- weight repack for MFMA B-fragments (3x3 convs) ----------------
__global__ void repack_w(const float* __restrict__ W, __hip_bfloat16* __restrict__ Wr,
                         int CIN, int COUT) {
  int NC = CIN / 32, NF = COUT / 16;
  int total = 9 * NC * NF * 512;
  for (int idx = blockIdx.x * blockDim.x + threadIdx.x; idx < total;
       idx += gridDim.x * blockDim.x) {
    int j = idx & 7, l = (idx >> 3) & 63;
    int rest = idx >> 9;
    int n = rest % NF; rest /= NF;
    int c = rest % NC; int t = rest / NC;
    int oc = n * 16 + (l & 15);
    int ic = c * 32 + (l >> 4) * 8 + j;
    Wr[idx] = __float2bfloat16(W[((size_t)oc * CIN + ic) * 9 + t]);
  }
}

// swizzle of the channel-block index by tile-local x (involution, bank-spreading)
template <int CBC>
__device__ inline int swz(int x) {
  if constexpr (CBC == 8) return x & 7;
  else return (x & 3) ^ ((x >> 2) & 3);
}

// ---------------- 3x3 conv via MFMA implicit GEMM + LDS-staged A ----------------
template <int CIN, int COUT, int HIN>
__global__ __launch_bounds__(256) void conv3x3_mfma(
    const __hip_bfloat16* __restrict__ in, __hip_bfloat16* __restrict__ out,
    const __hip_bfloat16* __restrict__ wb, const float* __restrict__ bias) {
  constexpr int HO = HIN - 2;
  constexpr int NC = CIN / 32;
  constexpr int NF = COUT / 16;
  constexpr int CBC = CIN / 8;             // 16B chunks per pixel
  constexpr int SH = (CBC == 8) ? 3 : 2;
  constexpr int TX = 18;
  constexpr int SLOTS = 18 * 18 * CBC;
  constexpr int ITERS = (SLOTS + 255) / 256;
  constexpr int ROWSTRIDE = TX * CBC * 16; // bytes per tile row
  __shared__ char lds[ITERS * 256 * 16];

  const int zb = blockIdx.z;
  const __hip_bfloat16* ip = in + (size_t)zb * HIN * HIN * CIN;
  __hip_bfloat16* op = out + (size_t)zb * HO * HO * COUT;
  const int lane = threadIdx.x & 63;
  const int wave = threadIdx.x >> 6;
  const int x0 = blockIdx.x * 16;
  const int y0 = blockIdx.y * 16;

  // ---- stage input tile ----
#pragma unroll
  for (int i = 0; i < ITERS; ++i) {
    int sbase = i * 256 + wave * 64;       // wave-uniform
    int slot = sbase + lane;
    slot = slot < SLOTS ? slot : SLOTS - 1;
    int pix = slot >> SH, scb = slot & (CBC - 1);
    int y = pix / TX, x = pix - y * TX;
    int cb = scb ^ swz<CBC>(x);
    int gy = min(y0 + y, HIN - 1), gx = min(x0 + x, HIN - 1);
    const __hip_bfloat16* src = ip + ((size_t)gy * HIN + gx) * CIN + cb * 8;
    gld16(src, lds + (size_t)sbase * 16);
  }
  __syncthreads();

  // ---- A-fragment LDS byte addresses (per kx, per 32-ch group) ----
  int abase[3][NC];
#pragma unroll
  for (int kx = 0; kx < 3; ++kx) {
#pragma unroll
    for (int c = 0; c < NC; ++c) {
      int x = (lane & 15) + kx;
      int cb = c * 4 + (lane >> 4);
      int slot = cb ^ swz<CBC>(x);
      abase[kx][c] = (x * CBC + slot) * 16 + wave * 4 * ROWSTRIDE;
    }
  }

  float bv[NF];
#pragma unroll
  for (int n = 0; n < NF; ++n) bv[n] = bias[n * 16 + (lane & 15)];
  float4_t acc[4][NF];
#pragma unroll
  for (int m = 0; m < 4; ++m)
#pragma unroll
    for (int n = 0; n < NF; ++n) acc[m][n] = {bv[n], bv[n], bv[n], bv[n]};

#pragma unroll
  for (int t = 0; t < 9; ++t) {
    const int ky = t / 3, kx = t % 3;
#pragma unroll
    for (int c = 0; c < NC; ++c) {
      short8_t B[NF];
#pragma unroll
      for (int n = 0; n < NF; ++n)
        B[n] = *reinterpret_cast<const short8_t*>(
            wb + (size_t)(((t * NC + c) * NF + n) * 64 + lane) * 8);
#pragma unroll
      for (int m = 0; m < 4; ++m) {
        short8_t A = *reinterpret_cast<const short8_t*>(
            lds + abase[kx][c] + (m + ky) * ROWSTRIDE);
#pragma unroll
        for (int n = 0; n < NF; ++n)
          acc[m][n] = __builtin_amdgcn_mfma_f32_16x16x32_bf16(A, B[n], acc[m][n], 0, 0, 0);
      }
    }
  }
  // epilogue: relu + NHWC bf16 store
#pragma unroll
  for (int m = 0; m < 4; ++m) {
    int yy = y0 + wave * 4 + m;
    if (yy < HO) {
#pragma unroll
      for (int r = 0; r < 4; ++r) {
        int xx = x0 + (lane >> 4) * 4 + r;
        if (xx < HO) {
#pragma unroll
          for (int n = 0; n < NF; ++n) {
            float v = acc[m][n][r];
            v = v > 0.0f ? v : 0.0f;
            op[((size_t)yy * HO + xx) * COUT + n * 16 + (lane & 15)] = __float2bfloat16(v);
          }
        }
      }
    }
  }
}

// ---------------- conv4: 3x3 32->16 MFMA + sigmoid + pixel_shuffle(r=4) ----------------
__global__ __launch_bounds__(256) void conv4_mfma(
    const __hip_bfloat16* __restrict__ in, float* __restrict__ out,
    const __hip_bfloat16* __restrict__ wb, const float* __restrict__ bias, int bBase) {
  constexpr int CIN = 32, HIN = HO3;
  constexpr int CBC = 4, SH = 2, TX = 18;
  constexpr int SLOTS = 18 * 18 * CBC;
  constexpr int ITERS = (SLOTS + 255) / 256;
  constexpr int ROWSTRIDE = TX * CBC * 16;
  __shared__ char lds[ITERS * 256 * 16];

  const int zb = blockIdx.z;
  const __hip_bfloat16* ip = in + (size_t)zb * HIN * HIN * CIN;
  const int lane = threadIdx.x & 63;
  const int wave = threadIdx.x >> 6;
  const int x0 = blockIdx.x * 16;
  const int y0 = blockIdx.y * 16;

#pragma unroll
  for (int i = 0; i < ITERS; ++i) {
    int sbase = i * 256 + wave * 64;
    int slot = sbase + lane;
    slot = slot < SLOTS ? slot : SLOTS - 1;
    int pix = slot >> SH, scb = slot & (CBC - 1);
    int y = pix / TX, x = pix - y * TX;
    int cb = scb ^ swz<CBC>(x);
    int gy = min(y0 + y, HIN - 1), gx = min(x0 + x, HIN - 1);
    const __hip_bfloat16* src = ip + ((size_t)gy * HIN + gx) * CIN + cb * 8;
    gld16(src, lds + (size_t)sbase * 16);
  }
  __syncthreads();

  int abase[3];
#pragma unroll
  for (int kx = 0; kx < 3; ++kx) {
    int x = (lane & 15) + kx;
    int cb = lane >> 4;
    int slot = cb ^ swz<CBC>(x);
    abase[kx] = (x * CBC + slot) * 16 + wave * 4 * ROWSTRIDE;
  }

  float bv = bias[lane & 15];
  float4_t acc[4];
#pragma unroll
  for (int m = 0; m < 4; ++m) acc[m] = {bv, bv, bv, bv};

#pragma unroll
  for (int t = 0; t < 9; ++t) {
    const int ky = t / 3, kx = t % 3;
    short8_t B = *reinterpret_cast<const short8_t*>(wb + (size_t)(t * 64 + lane) * 8);
#pragma unroll
    for (int m = 0; m < 4; ++m) {
      short8_t A = *reinterpret_cast<const short8_t*>(
          lds + abase[kx] + (m + ky) * ROWSTRIDE);
      acc[m] = __builtin_amdgcn_mfma_f32_16x16x32_bf16(A, B, acc[m], 0, 0, 0);
    }
  }
  // sigmoid + pixel_shuffle: oc = lane&15 -> (i,j) = (oc>>2, oc&3)
  float* ob = out + (size_t)(bBase + zb) * 1024 * 1024;
  const int oc = lane & 15;
#pragma unroll
  for (int m = 0; m < 4; ++m) {
    int yy = y0 + wave * 4 + m;
#pragma unroll
    for (int r = 0; r < 4; ++r) {
      int xx = x0 + (lane >> 4) * 4 + r;
      float v = 1.0f / (1.0f + expf(-acc[m][r]));
      ob[(size_t)(yy * 4 + (oc >> 2)) * 1024 + xx * 4 + (oc & 3)] = v;
    }
  }
}

extern "C" void kernel_launch(void* const* d_in, const int* in_sizes, int n_in,
                              void* d_out, int out_size, void* d_ws, size_t ws_size,
                              hipStream_t stream) {
  const float* x  = (const float*)d_in[0];
  const float* W1 = (const float*)d_in[1];
  const float* b1 = (const float*)d_in[2];
  const float* W2 = (const float*)d_in[3];
  const float* b2 = (const float*)d_in[4];
  const float* W3 = (const float*)d_in[5];
  const float* b3 = (const float*)d_in[6];
  const float* W4 = (const float*)d_in[7];
  const float* b4 = (const float*)d_in[8];
  float* out = (float*)d_out;

  __hip_bfloat16* wr1 = (__hip_bfloat16*)d_ws;   // 2048 elems
  __hip_bfloat16* wr2 = wr1 + 2048;              // 18432
  __hip_bfloat16* wr3 = wr2 + 18432;             // 9216
  __hip_bfloat16* wr4 = wr3 + 9216;              // 4608
  char* base = (char*)d_ws + 131072;

  const size_t xp_sz = (size_t)WPD * WPD * sizeof(float);
  const size_t h1_sz = (size_t)HO1 * HO1 * 64 * sizeof(__hip_bfloat16);
  const size_t h2_sz = (size_t)HO2 * HO2 * 32 * sizeof(__hip_bfloat16);
  const size_t h3_sz = (size_t)HO3 * HO3 * 32 * sizeof(__hip_bfloat16);
  const size_t per_b = xp_sz + h1_sz + h2_sz + h3_sz;

  int g = (int)((ws_size - 131072) / per_b);
  if (g > 16) g = 16;
  if (g < 1) g = 1;

  float* xp = (float*)base;
  __hip_bfloat16* h1 = (__hip_bfloat16*)(base + (size_t)g * xp_sz);
  __hip_bfloat16* h2 = (__hip_bfloat16*)((char*)h1 + (size_t)g * h1_sz);
  __hip_bfloat16* h3 = (__hip_bfloat16*)((char*)h2 + (size_t)g * h2_sz);

  repack_w1<<<8, 256, 0, stream>>>(W1, wr1);
  repack_w<<<72, 256, 0, stream>>>(W2, wr2, 64, 32);
  repack_w<<<36, 256, 0, stream>>>(W3, wr3, 32, 32);
  repack_w<<<18, 256, 0, stream>>>(W4, wr4, 32, 16);

  for (int bBase = 0; bBase < 16; bBase += g) {
    int gc = min(g, 16 - bBase);
    size_t tot = (size_t)gc * WPD * WPD;
    int fillBlocks = (int)min((tot + 255) / 256, (size_t)2048);
    pad_fill_kernel<<<fillBlocks, 256, 0, stream>>>(x, xp, bBase, gc);
    extrap_kernel<<<gc, 256, 0, stream>>>(xp);
    conv1_mfma<<<dim3(17, 17, gc), 256, 0, stream>>>(xp, h1, wr1, b1);
    conv3x3_mfma<64, 32, HO1><<<dim3(17, 17, gc), 256, 0, stream>>>(h1, h2, wr2, b2);
    conv3x3_mfma<32, 32, HO2><<<dim3(17, 17, gc), 256, 0, stream>>>(h2, h3, wr3, b3);
    conv4_mfma<<<dim3(16, 16, gc), 256, 0, stream>>>(h3, out, wr4, b4, bBase);
  }
}

// Round 6
// 261.064 us; speedup vs baseline: 6.1893x; 1.0094x over previous
//
#include <hip/hip_runtime.h>
#include <hip/hip_bf16.h>
#include <math.h>

// Geometry
#define WPD 266   // padded H=W
#define HO1 262   // after 5x5
#define HO2 260
#define HO3 258
#define HO4 256

typedef __attribute__((ext_vector_type(8))) short short8_t;
typedef __attribute__((ext_vector_type(4))) float float4_t;

__device__ inline void gld16(const void* g, void* l) {
  __builtin_amdgcn_global_load_lds(
      (const __attribute__((address_space(1))) void*)g,
      (__attribute__((address_space(3))) void*)l, 16, 0, 0);
}

// ---------------- pad fill: xp = pad(x, 5, value=0.5) ----------------
__global__ void pad_fill_kernel(const float* __restrict__ x, float* __restrict__ xp,
                                int bBase, int gc) {
  size_t total = (size_t)gc * WPD * WPD;
  for (size_t idx = (size_t)blockIdx.x * blockDim.x + threadIdx.x; idx < total;
       idx += (size_t)gridDim.x * blockDim.x) {
    size_t zb = idx / (WPD * WPD);
    int rem = (int)(idx % (WPD * WPD));
    int y = rem / WPD, xx = rem % WPD;
    float v = 0.5f;
    if (y >= 5 && y < 261 && xx >= 5 && xx < 261)
      v = x[((size_t)(bBase + zb) * 256 + (y - 5)) * 256 + (xx - 5)];
    xp[idx] = v;
  }
}

// ---------------- border extrapolation (sequential rings i=5..1) ----------------
__global__ void extrap_kernel(float* __restrict__ xp) {
  const int W = WPD, H = WPD;
  float* p = xp + (size_t)blockIdx.x * W * W;
  for (int i = 5; i >= 1; --i) {
    int ip = i + 1, im = i - 1;
    int L = W - 2 * ip;
    for (int t = threadIdx.x; t < 4 * L; t += blockDim.x) {
      int e = t / L, j = t % L;
      float a;
      if (e == 0) {
        a = (p[i * W + i + j] + p[i * W + i + j + 1] + p[i * W + i + j + 2]) / 3.0f;
        p[im * W + ip + j] = a > 0.3f ? 1.0f : a;
      } else if (e == 1) {
        const float* r = p + (H - ip) * W;
        a = (r[i + j] + r[i + j + 1] + r[i + j + 2]) / 3.0f;
        p[(H - i) * W + ip + j] = a > 0.3f ? 1.0f : a;
      } else if (e == 2) {
        a = (p[(i + j) * W + i] + p[(i + j + 1) * W + i] + p[(i + j + 2) * W + i]) / 3.0f;
        p[(ip + j) * W + im] = a > 0.3f ? 1.0f : a;
      } else {
        a = (p[(i + j) * W + (W - ip)] + p[(i + j + 1) * W + (W - ip)] +
             p[(i + j + 2) * W + (W - ip)]) / 3.0f;
        p[(ip + j) * W + (W - i)] = a > 0.3f ? 1.0f : a;
      }
    }
    __syncthreads();
    if (threadIdx.x < 4) {
      int c = threadIdx.x;
      int cx, cy, nx, ny;
      if (c == 0)      { cx = im;    cy = im;    nx = 1;  ny = 1;  }
      else if (c == 1) { cx = W - i; cy = im;    nx = -1; ny = 1;  }
      else if (c == 2) { cx = W - i; cy = H - i; nx = -1; ny = -1; }
      else             { cx = im;    cy = H - i; nx = 1;  ny = -1; }
      int cxp = cx + nx, cyp = cy + ny;
      p[cy * W + cxp] = (p[cyp * W + cxp] + p[cy * W + cx + 2 * nx]) * 0.5f;
      p[cyp * W + cx] = (p[cyp * W + cxp] + p[(cy + 2 * ny) * W + cx]) * 0.5f;
      p[cy * W + cx]  = (p[cy * W + cxp] + p[cyp * W + cx]) * 0.5f;
    }
    __syncthreads();
  }
}

// ---------------- conv1 weight repack: Wr[n][lane][j] = W1[oc][tap], tap>=25 -> 0 ----
__global__ void repack_w1(const float* __restrict__ W, __hip_bfloat16* __restrict__ Wr) {
  int idx = blockIdx.x * blockDim.x + threadIdx.x;
  if (idx < 2048) {
    int j = idx & 7, l = (idx >> 3) & 63, n = idx >> 9;
    int oc = n * 16 + (l & 15);
    int tap = (l >> 4) * 8 + j;
    Wr[idx] = __float2bfloat16(tap < 25 ? W[oc * 25 + tap] : 0.0f);
  }
}

// ---------------- conv1: 5x5 1->64 via MFMA (K=25 taps padded to 32) ----------------
__global__ __launch_bounds__(256) void conv1_mfma(
    const float* __restrict__ xp, __hip_bfloat16* __restrict__ h1,
    const __hip_bfloat16* __restrict__ wb, const float* __restrict__ b1) {
  const int HIN = WPD, HO = HO1;
  const int zb = blockIdx.z;
  const float* p = xp + (size_t)zb * HIN * HIN;
  const int x0 = blockIdx.x * 16, y0 = blockIdx.y * 16;
  const int lane = threadIdx.x & 63;
  const int wave = threadIdx.x >> 6;
  const int lx = lane & 15, kg = lane >> 4;
  const int ly = wave * 4;

  __shared__ short tile[24 * 20];  // rows 0..19 data, 20..23 zeros
  for (int idx = threadIdx.x; idx < 24 * 20; idx += 256) {
    int r = idx / 20, c = idx % 20;
    short v = 0;
    if (r < 20) {
      int yy = min(y0 + r, HIN - 1), xx = min(x0 + c, HIN - 1);
      __hip_bfloat16 h = __float2bfloat16(p[yy * HIN + xx]);
      v = *reinterpret_cast<short*>(&h);
    }
    tile[idx] = v;
  }
  __syncthreads();

  int aoff[8];
#pragma unroll
  for (int j = 0; j < 8; ++j) {
    int tap = kg * 8 + j;
    int ky = tap / 5, kx = tap % 5;
    aoff[j] = (tap < 25) ? ((ly + ky) * 20 + kx + lx) : (20 * 20 + lx);
  }

  float bv[4];
#pragma unroll
  for (int n = 0; n < 4; ++n) bv[n] = b1[n * 16 + lx];
  float4_t acc[4][4];
#pragma unroll
  for (int m = 0; m < 4; ++m)
#pragma unroll
    for (int n = 0; n < 4; ++n) acc[m][n] = {bv[n], bv[n], bv[n], bv[n]};

  short8_t B[4];
#pragma unroll
  for (int n = 0; n < 4; ++n)
    B[n] = *reinterpret_cast<const short8_t*>(wb + (size_t)(n * 64 + lane) * 8);

#pragma unroll
  for (int m = 0; m < 4; ++m) {
    short8_t A;
#pragma unroll
    for (int j = 0; j < 8; ++j) A[j] = tile[aoff[j] + m * 20];
#pragma unroll
    for (int n = 0; n < 4; ++n)
      acc[m][n] = __builtin_amdgcn_mfma_f32_16x16x32_bf16(A, B[n], acc[m][n], 0, 0, 0);
  }

  __hip_bfloat16* op = h1 + (size_t)zb * HO * HO * 64;
#pragma unroll
  for (int m = 0; m < 4; ++m) {
    int yy = y0 + ly + m;
    if (yy < HO) {
#pragma unroll
      for (int r = 0; r < 4; ++r) {
        int xx = x0 + kg * 4 + r;
        if (xx < HO) {
#pragma unroll
          for (int n = 0; n < 4; ++n) {
            float v = acc[m][n][r];
            v = v > 0.0f ? v : 0.0f;
            op[((size_t)yy * HO + xx) * 64 + n * 16 + lx] = __float2bfloat16(v);
          }
        }
      }
    }
  }
}

// ---------------- weight repack for MFMA B-fragments (3x3 convs) ----------------
__global__ void repack_w(const float* __restrict__ W, __hip_bfloat16* __restrict__ Wr,
                         int CIN, int COUT) {
  int NC = CIN / 32, NF = COUT / 16;
  int total = 9 * NC * NF * 512;
  for (int idx = blockIdx.x * blockDim.x + threadIdx.x; idx < total;
       idx += gridDim.x * blockDim.x) {
    int j = idx & 7, l = (idx >> 3) & 63;
    int rest = idx >> 9;
    int n = rest % NF; rest /= NF;
    int c = rest % NC; int t = rest / NC;
    int oc = n * 16 + (l & 15);
    int ic = c * 32 + (l >> 4) * 8 + j;
    Wr[idx] = __float2bfloat16(W[((size_t)oc * CIN + ic) * 9 + t]);
  }
}

// involutive bank-spreading swizzle of the 4-chunk index by tile-local x
__device__ inline int swz4(int x) { return (x & 3) ^ ((x >> 2) & 3); }

// ---------------- 3x3 conv via MFMA implicit GEMM + LDS-staged A ----------------
// 32-channel phases against ONE 24KB LDS buffer -> 6 blocks/CU residency.
template <int CIN, int COUT, int HIN>
__global__ __launch_bounds__(256, 4) void conv3x3_mfma(
    const __hip_bfloat16* __restrict__ in, __hip_bfloat16* __restrict__ out,
    const __hip_bfloat16* __restrict__ wb, const float* __restrict__ bias) {
  constexpr int HO = HIN - 2;
  constexpr int NPH = CIN / 32;            // channel phases
  constexpr int NF = COUT / 16;
  constexpr int TX = 18;
  constexpr int SLOTS = TX * TX * 4;       // 4 x 16B chunks per pixel (32 ch)
  constexpr int ITERS = (SLOTS + 255) / 256;
  constexpr int ROWSTRIDE = TX * 4 * 16;   // bytes per tile row
  __shared__ char lds[ITERS * 256 * 16];   // 24 KB

  const int zb = blockIdx.z;
  const __hip_bfloat16* ip = in + (size_t)zb * HIN * HIN * CIN;
  __hip_bfloat16* op = out + (size_t)zb * HO * HO * COUT;
  const int lane = threadIdx.x & 63;
  const int wave = threadIdx.x >> 6;
  const int x0 = blockIdx.x * 16;
  const int y0 = blockIdx.y * 16;

  // ---- A-fragment LDS byte addresses (per kx) ----
  int abase[3];
#pragma unroll
  for (int kx = 0; kx < 3; ++kx) {
    int x = (lane & 15) + kx;
    int slot = (lane >> 4) ^ swz4(x);
    abase[kx] = (x * 4 + slot) * 16 + wave * 4 * ROWSTRIDE;
  }

  // ---- staging source precompute (per-iter pixel/chunk decomposition) ----
  float bv[NF];
#pragma unroll
  for (int n = 0; n < NF; ++n) bv[n] = bias[n * 16 + (lane & 15)];
  float4_t acc[4][NF];
#pragma unroll
  for (int m = 0; m < 4; ++m)
#pragma unroll
    for (int n = 0; n < NF; ++n) acc[m][n] = {bv[n], bv[n], bv[n], bv[n]};

#pragma unroll
  for (int ph = 0; ph < NPH; ++ph) {
    // stage channels [ph*32, ph*32+32) of the 18x18 tile
#pragma unroll
    for (int i = 0; i < ITERS; ++i) {
      int sbase = i * 256 + wave * 64;     // wave-uniform
      int slot = sbase + lane;
      slot = slot < SLOTS ? slot : SLOTS - 1;
      int pix = slot >> 2, scb = slot & 3;
      int y = pix / TX, x = pix - y * TX;
      int cb = scb ^ swz4(x);
      int gy = min(y0 + y, HIN - 1), gx = min(x0 + x, HIN - 1);
      const __hip_bfloat16* src = ip + ((size_t)gy * HIN + gx) * CIN + ph * 32 + cb * 8;
      gld16(src, lds + (size_t)sbase * 16);
    }
    __syncthreads();                       // staging complete

#pragma unroll
    for (int t = 0; t < 9; ++t) {
      const int ky = t / 3, kx = t % 3;
      short8_t B[NF];
#pragma unroll
      for (int n = 0; n < NF; ++n)
        B[n] = *reinterpret_cast<const short8_t*>(
            wb + (size_t)(((t * NPH + ph) * NF + n) * 64 + lane) * 8);
#pragma unroll
      for (int m = 0; m < 4; ++m) {
        short8_t A = *reinterpret_cast<const short8_t*>(
            lds + abase[kx] + (m + ky) * ROWSTRIDE);
#pragma unroll
        for (int n = 0; n < NF; ++n)
          acc[m][n] = __builtin_amdgcn_mfma_f32_16x16x32_bf16(A, B[n], acc[m][n], 0, 0, 0);
      }
    }
    if (ph + 1 < NPH) __syncthreads();     // protect buffer overwrite
  }

  // epilogue: relu + NHWC bf16 store
#pragma unroll
  for (int m = 0; m < 4; ++m) {
    int yy = y0 + wave * 4 + m;
    if (yy < HO) {
#pragma unroll
      for (int r = 0; r < 4; ++r) {
        int xx = x0 + (lane >> 4) * 4 + r;
        if (xx < HO) {
#pragma unroll
          for (int n = 0; n < NF; ++n) {
            float v = acc[m][n][r];
            v = v > 0.0f ? v : 0.0f;
            op[((size_t)yy * HO + xx) * COUT + n * 16 + (lane & 15)] = __float2bfloat16(v);
          }
        }
      }
    }
  }
}

// ---------------- conv4: 3x3 32->16 MFMA + sigmoid + pixel_shuffle(r=4) ----------------
__global__ __launch_bounds__(256, 4) void conv4_mfma(
    const __hip_bfloat16* __restrict__ in, float* __restrict__ out,
    const __hip_bfloat16* __restrict__ wb, const float* __restrict__ bias, int bBase) {
  constexpr int CIN = 32, HIN = HO3;
  constexpr int TX = 18;
  constexpr int SLOTS = TX * TX * 4;
  constexpr int ITERS = (SLOTS + 255) / 256;
  constexpr int ROWSTRIDE = TX * 4 * 16;
  __shared__ char lds[ITERS * 256 * 16];

  const int zb = blockIdx.z;
  const __hip_bfloat16* ip = in + (size_t)zb * HIN * HIN * CIN;
  const int lane = threadIdx.x & 63;
  const int wave = threadIdx.x >> 6;
  const int x0 = blockIdx.x * 16;
  const int y0 = blockIdx.y * 16;

#pragma unroll
  for (int i = 0; i < ITERS; ++i) {
    int sbase = i * 256 + wave * 64;
    int slot = sbase + lane;
    slot = slot < SLOTS ? slot : SLOTS - 1;
    int pix = slot >> 2, scb = slot & 3;
    int y = pix / TX, x = pix - y * TX;
    int cb = scb ^ swz4(x);
    int gy = min(y0 + y, HIN - 1), gx = min(x0 + x, HIN - 1);
    const __hip_bfloat16* src = ip + ((size_t)gy * HIN + gx) * CIN + cb * 8;
    gld16(src, lds + (size_t)sbase * 16);
  }
  __syncthreads();

  int abase[3];
#pragma unroll
  for (int kx = 0; kx < 3; ++kx) {
    int x = (lane & 15) + kx;
    int slot = (lane >> 4) ^ swz4(x);
    abase[kx] = (x * 4 + slot) * 16 + wave * 4 * ROWSTRIDE;
  }

  float bv = bias[lane & 15];
  float4_t acc[4];
#pragma unroll
  for (int m = 0; m < 4; ++m) acc[m] = {bv, bv, bv, bv};

#pragma unroll
  for (int t = 0; t < 9; ++t) {
    const int ky = t / 3, kx = t % 3;
    short8_t B = *reinterpret_cast<const short8_t*>(wb + (size_t)(t * 64 + lane) * 8);
#pragma unroll
    for (int m = 0; m < 4; ++m) {
      short8_t A = *reinterpret_cast<const short8_t*>(
          lds + abase[kx] + (m + ky) * ROWSTRIDE);
      acc[m] = __builtin_amdgcn_mfma_f32_16x16x32_bf16(A, B, acc[m], 0, 0, 0);
    }
  }
  float* ob = out + (size_t)(bBase + zb) * 1024 * 1024;
  const int oc = lane & 15;
#pragma unroll
  for (int m = 0; m < 4; ++m) {
    int yy = y0 + wave * 4 + m;
#pragma unroll
    for (int r = 0; r < 4; ++r) {
      int xx = x0 + (lane >> 4) * 4 + r;
      float v = 1.0f / (1.0f + expf(-acc[m][r]));
      ob[(size_t)(yy * 4 + (oc >> 2)) * 1024 + xx * 4 + (oc & 3)] = v;
    }
  }
}

extern "C" void kernel_launch(void* const* d_in, const int* in_sizes, int n_in,
                              void* d_out, int out_size, void* d_ws, size_t ws_size,
                              hipStream_t stream) {
  const float* x  = (const float*)d_in[0];
  const float* W1 = (const float*)d_in[1];
  const float* b1 = (const float*)d_in[2];
  const float* W2 = (const float*)d_in[3];
  const float* b2 = (const float*)d_in[4];
  const float* W3 = (const float*)d_in[5];
  const float* b3 = (const float*)d_in[6];
  const float* W4 = (const float*)d_in[7];
  const float* b4 = (const float*)d_in[8];
  float* out = (float*)d_out;

  __hip_bfloat16* wr1 = (__hip_bfloat16*)d_ws;   // 2048 elems
  __hip_bfloat16* wr2 = wr1 + 2048;              // 18432
  __hip_bfloat16* wr3 = wr2 + 18432;             // 9216
  __hip_bfloat16* wr4 = wr3 + 9216;              // 4608
  char* base = (char*)d_ws + 131072;

  const size_t xp_sz = (size_t)WPD * WPD * sizeof(float);
  const size_t h1_sz = (size_t)HO1 * HO1 * 64 * sizeof(__hip_bfloat16);
  const size_t h2_sz = (size_t)HO2 * HO2 * 32 * sizeof(__hip_bfloat16);
  const size_t h3_sz = (size_t)HO3 * HO3 * 32 * sizeof(__hip_bfloat16);
  const size_t per_b = xp_sz + h1_sz + h2_sz + h3_sz;

  int g = (int)((ws_size - 131072) / per_b);
  if (g > 16) g = 16;
  if (g < 1) g = 1;

  float* xp = (float*)base;
  __hip_bfloat16* h1 = (__hip_bfloat16*)(base + (size_t)g * xp_sz);
  __hip_bfloat16* h2 = (__hip_bfloat16*)((char*)h1 + (size_t)g * h1_sz);
  __hip_bfloat16* h3 = (__hip_bfloat16*)((char*)h2 + (size_t)g * h2_sz);

  repack_w1<<<8, 256, 0, stream>>>(W1, wr1);
  repack_w<<<72, 256, 0, stream>>>(W2, wr2, 64, 32);
  repack_w<<<36, 256, 0, stream>>>(W3, wr3, 32, 32);
  repack_w<<<18, 256, 0, stream>>>(W4, wr4, 32, 16);

  for (int bBase = 0; bBase < 16; bBase += g) {
    int gc = min(g, 16 - bBase);
    size_t tot = (size_t)gc * WPD * WPD;
    int fillBlocks = (int)min((tot + 255) / 256, (size_t)2048);
    pad_fill_kernel<<<fillBlocks, 256, 0, stream>>>(x, xp, bBase, gc);
    extrap_kernel<<<gc, 256, 0, stream>>>(xp);
    conv1_mfma<<<dim3(17, 17, gc), 256, 0, stream>>>(xp, h1, wr1, b1);
    conv3x3_mfma<64, 32, HO1><<<dim3(17, 17, gc), 256, 0, stream>>>(h1, h2, wr2, b2);
    conv3x3_mfma<32, 32, HO2><<<dim3(17, 17, gc), 256, 0, stream>>>(h2, h3, wr3, b3);
    conv4_mfma<<<dim3(16, 16, gc), 256, 0, stream>>>(h3, out, wr4, b4, bBase);
  }
}

// Round 7
// 232.928 us; speedup vs baseline: 6.9369x; 1.1208x over previous
//
#include <hip/hip_runtime.h>
#include <hip/hip_bf16.h>
#include <math.h>

// Geometry
#define WPD 266   // padded H=W
#define HO1 262   // after 5x5 (virtual now; h1 lives only in LDS)
#define HO2 260
#define HO3 258
#define HO4 256

typedef __attribute__((ext_vector_type(8))) short short8_t;
typedef __attribute__((ext_vector_type(4))) float float4_t;

__device__ inline void gld16(const void* g, void* l) {
  __builtin_amdgcn_global_load_lds(
      (const __attribute__((address_space(1))) void*)g,
      (__attribute__((address_space(3))) void*)l, 16, 0, 0);
}

// ---------------- pad fill: xp = pad(x, 5, value=0.5) ----------------
__global__ void pad_fill_kernel(const float* __restrict__ x, float* __restrict__ xp,
                                int bBase, int gc) {
  size_t total = (size_t)gc * WPD * WPD;
  for (size_t idx = (size_t)blockIdx.x * blockDim.x + threadIdx.x; idx < total;
       idx += (size_t)gridDim.x * blockDim.x) {
    size_t zb = idx / (WPD * WPD);
    int rem = (int)(idx % (WPD * WPD));
    int y = rem / WPD, xx = rem % WPD;
    float v = 0.5f;
    if (y >= 5 && y < 261 && xx >= 5 && xx < 261)
      v = x[((size_t)(bBase + zb) * 256 + (y - 5)) * 256 + (xx - 5)];
    xp[idx] = v;
  }
}

// ---------------- border extrapolation (sequential rings i=5..1) ----------------
__global__ void extrap_kernel(float* __restrict__ xp) {
  const int W = WPD, H = WPD;
  float* p = xp + (size_t)blockIdx.x * W * W;
  for (int i = 5; i >= 1; --i) {
    int ip = i + 1, im = i - 1;
    int L = W - 2 * ip;
    for (int t = threadIdx.x; t < 4 * L; t += blockDim.x) {
      int e = t / L, j = t % L;
      float a;
      if (e == 0) {
        a = (p[i * W + i + j] + p[i * W + i + j + 1] + p[i * W + i + j + 2]) / 3.0f;
        p[im * W + ip + j] = a > 0.3f ? 1.0f : a;
      } else if (e == 1) {
        const float* r = p + (H - ip) * W;
        a = (r[i + j] + r[i + j + 1] + r[i + j + 2]) / 3.0f;
        p[(H - i) * W + ip + j] = a > 0.3f ? 1.0f : a;
      } else if (e == 2) {
        a = (p[(i + j) * W + i] + p[(i + j + 1) * W + i] + p[(i + j + 2) * W + i]) / 3.0f;
        p[(ip + j) * W + im] = a > 0.3f ? 1.0f : a;
      } else {
        a = (p[(i + j) * W + (W - ip)] + p[(i + j + 1) * W + (W - ip)] +
             p[(i + j + 2) * W + (W - ip)]) / 3.0f;
        p[(ip + j) * W + (W - i)] = a > 0.3f ? 1.0f : a;
      }
    }
    __syncthreads();
    if (threadIdx.x < 4) {
      int c = threadIdx.x;
      int cx, cy, nx, ny;
      if (c == 0)      { cx = im;    cy = im;    nx = 1;  ny = 1;  }
      else if (c == 1) { cx = W - i; cy = im;    nx = -1; ny = 1;  }
      else if (c == 2) { cx = W - i; cy = H - i; nx = -1; ny = -1; }
      else             { cx = im;    cy = H - i; nx = 1;  ny = -1; }
      int cxp = cx + nx, cyp = cy + ny;
      p[cy * W + cxp] = (p[cyp * W + cxp] + p[cy * W + cx + 2 * nx]) * 0.5f;
      p[cyp * W + cx] = (p[cyp * W + cxp] + p[(cy + 2 * ny) * W + cx]) * 0.5f;
      p[cy * W + cx]  = (p[cy * W + cxp] + p[cyp * W + cx]) * 0.5f;
    }
    __syncthreads();
  }
}

// ---------------- conv1 weight repack: Wr[n][lane][j] = W1[oc][tap], tap>=25 -> 0 ----
__global__ void repack_w1(const float* __restrict__ W, __hip_bfloat16* __restrict__ Wr) {
  int idx = blockIdx.x * blockDim.x + threadIdx.x;
  if (idx < 2048) {
    int j = idx & 7, l = (idx >> 3) & 63, n = idx >> 9;
    int oc = n * 16 + (l & 15);
    int tap = (l >> 4) * 8 + j;
    Wr[idx] = __float2bfloat16(tap < 25 ? W[oc * 25 + tap] : 0.0f);
  }
}

// ---------------- weight repack for MFMA B-fragments (3x3 convs) ----------------
__global__ void repack_w(const float* __restrict__ W, __hip_bfloat16* __restrict__ Wr,
                         int CIN, int COUT) {
  int NC = CIN / 32, NF = COUT / 16;
  int total = 9 * NC * NF * 512;
  for (int idx = blockIdx.x * blockDim.x + threadIdx.x; idx < total;
       idx += gridDim.x * blockDim.x) {
    int j = idx & 7, l = (idx >> 3) & 63;
    int rest = idx >> 9;
    int n = rest % NF; rest /= NF;
    int c = rest % NC; int t = rest / NC;
    int oc = n * 16 + (l & 15);
    int ic = c * 32 + (l >> 4) * 8 + j;
    Wr[idx] = __float2bfloat16(W[((size_t)oc * CIN + ic) * 9 + t]);
  }
}

// involutive bank-spreading swizzle of the 4-chunk index by tile-local x
__device__ inline int swz4(int x) { return (x & 3) ^ ((x >> 2) & 3); }

// ---------------- fused conv1(5x5,1->64)+conv2(3x3,64->32): h1 stays in LDS ----
// Block = 16x16 h2 outputs. xp patch 22x22 bf16 in lds1 (+zero pad rows).
// Per oc-phase (32 of 64 h1 channels): conv1 MFMA over linearized 18x18 h1
// region -> swizzled lds2 tile -> conv2 9-tap MFMA (existing pattern).
__global__ __launch_bounds__(256, 4) void conv12_mfma(
    const float* __restrict__ xp, __hip_bfloat16* __restrict__ h2,
    const __hip_bfloat16* __restrict__ w1r, const float* __restrict__ b1,
    const __hip_bfloat16* __restrict__ w2r, const float* __restrict__ b2) {
  const int HIN = WPD;        // xp 266
  const int HO = HO2;         // 260
  const int zb = blockIdx.z;
  const float* p = xp + (size_t)zb * HIN * HIN;
  const int x0 = blockIdx.x * 16, y0 = blockIdx.y * 16;
  const int lane = threadIdx.x & 63;
  const int wave = threadIdx.x >> 6;
  const int lx = lane & 15, kg = lane >> 4;

  __shared__ short lds1[26 * 22];   // rows 0..21 xp data, 22..25 zeros
  __shared__ char lds2[18 * 1152];  // 18x18 x 32ch bf16, chunk-swizzled

  // ---- stage xp patch (f32 -> bf16), zero pad rows ----
  for (int idx = threadIdx.x; idx < 26 * 22; idx += 256) {
    int r = idx / 22, c = idx % 22;
    short v = 0;
    if (r < 22) {
      int yy = min(y0 + r, HIN - 1), xx = min(x0 + c, HIN - 1);
      __hip_bfloat16 h = __float2bfloat16(p[yy * HIN + xx]);
      v = *reinterpret_cast<short*>(&h);
    }
    lds1[idx] = v;
  }

  // conv1 tap offsets (lane-dependent, phase-independent)
  int toff[8]; bool tvalid[8];
#pragma unroll
  for (int j = 0; j < 8; ++j) {
    int tap = kg * 8 + j;
    int ky = tap / 5, kx = tap - ky * 5;
    tvalid[j] = tap < 25;
    toff[j] = ky * 22 + kx;
  }
  // conv1 per-mi A base (pixel-linearized over 18x18)
  int bse[6];
#pragma unroll
  for (int mi = 0; mi < 6; ++mi) {
    int pp = mi * 64 + wave * 16 + lx;
    pp = pp < 324 ? pp : 323;
    int y1 = pp / 18, x1 = pp - y1 * 18;
    bse[mi] = y1 * 22 + x1;
  }
  // conv2 A-fragment byte bases (per kx)
  int abase[3];
#pragma unroll
  for (int kx = 0; kx < 3; ++kx) {
    int x = lx + kx;
    int slot = kg ^ swz4(x);
    abase[kx] = (x * 4 + slot) * 16 + wave * 4 * 1152;
  }

  float bv2[2];
#pragma unroll
  for (int n = 0; n < 2; ++n) bv2[n] = b2[n * 16 + lx];
  float4_t acc2[4][2];
#pragma unroll
  for (int m = 0; m < 4; ++m)
#pragma unroll
    for (int n = 0; n < 2; ++n) acc2[m][n] = {bv2[n], bv2[n], bv2[n], bv2[n]};

  __syncthreads();  // lds1 ready

#pragma unroll
  for (int ph = 0; ph < 2; ++ph) {
    // ---- conv1: 32 oc of this phase over 324 pixels (register-only vs lds2) ----
    short8_t B1[2];
    float4_t a1[6][2];
#pragma unroll
    for (int n2 = 0; n2 < 2; ++n2) {
      B1[n2] = *reinterpret_cast<const short8_t*>(w1r + (size_t)((ph * 2 + n2) * 64 + lane) * 8);
      float bb = b1[(ph * 2 + n2) * 16 + lx];
#pragma unroll
      for (int mi = 0; mi < 6; ++mi) a1[mi][n2] = {bb, bb, bb, bb};
    }
#pragma unroll
    for (int mi = 0; mi < 6; ++mi) {
      int pb = mi * 64 + wave * 16;
      if (pb < 324) {
        short8_t A;
#pragma unroll
        for (int j = 0; j < 8; ++j)
          A[j] = lds1[tvalid[j] ? bse[mi] + toff[j] : 484 + lx];
#pragma unroll
        for (int n2 = 0; n2 < 2; ++n2)
          a1[mi][n2] = __builtin_amdgcn_mfma_f32_16x16x32_bf16(A, B1[n2], a1[mi][n2], 0, 0, 0);
      }
    }
    if (ph) __syncthreads();  // previous conv2 phase done reading lds2
    // ---- store relu'd h1 phase-channels into swizzled lds2 ----
#pragma unroll
    for (int mi = 0; mi < 6; ++mi) {
      int pb = mi * 64 + wave * 16;
      if (pb < 324) {
#pragma unroll
        for (int r = 0; r < 4; ++r) {
          int pd = pb + kg * 4 + r;
          if (pd < 324) {
            int y2 = pd / 18, x2 = pd - y2 * 18;
#pragma unroll
            for (int n2 = 0; n2 < 2; ++n2) {
              int cb = n2 * 2 + (lx >> 3);
              int slot = cb ^ swz4(x2);
              float v = a1[mi][n2][r];
              v = v > 0.0f ? v : 0.0f;
              __hip_bfloat16 h = __float2bfloat16(v);
              *reinterpret_cast<short*>(lds2 + y2 * 1152 + (x2 * 4 + slot) * 16 +
                                        (lx & 7) * 2) = *reinterpret_cast<short*>(&h);
            }
          }
        }
      }
    }
    __syncthreads();  // lds2 ready
    // ---- conv2 phase: 9-tap MFMA over lds2 ----
#pragma unroll
    for (int t = 0; t < 9; ++t) {
      const int ky = t / 3, kx = t % 3;
      short8_t B2[2];
#pragma unroll
      for (int n = 0; n < 2; ++n)
        B2[n] = *reinterpret_cast<const short8_t*>(
            w2r + (size_t)(((t * 2 + ph) * 2 + n) * 64 + lane) * 8);
#pragma unroll
      for (int m = 0; m < 4; ++m) {
        short8_t A = *reinterpret_cast<const short8_t*>(lds2 + abase[kx] + (m + ky) * 1152);
#pragma unroll
        for (int n = 0; n < 2; ++n)
          acc2[m][n] = __builtin_amdgcn_mfma_f32_16x16x32_bf16(A, B2[n], acc2[m][n], 0, 0, 0);
      }
    }
  }

  // ---- epilogue: relu + NHWC bf16 store of h2 ----
  __hip_bfloat16* op = h2 + (size_t)zb * HO * HO * 32;
#pragma unroll
  for (int m = 0; m < 4; ++m) {
    int yy = y0 + wave * 4 + m;
    if (yy < HO) {
#pragma unroll
      for (int r = 0; r < 4; ++r) {
        int xx = x0 + kg * 4 + r;
        if (xx < HO) {
#pragma unroll
          for (int n = 0; n < 2; ++n) {
            float v = acc2[m][n][r];
            v = v > 0.0f ? v : 0.0f;
            op[((size_t)yy * HO + xx) * 32 + n * 16 + lx] = __float2bfloat16(v);
          }
        }
      }
    }
  }
}

// ---------------- 3x3 conv via MFMA implicit GEMM + LDS-staged A ----------------
template <int CIN, int COUT, int HIN>
__global__ __launch_bounds__(256, 4) void conv3x3_mfma(
    const __hip_bfloat16* __restrict__ in, __hip_bfloat16* __restrict__ out,
    const __hip_bfloat16* __restrict__ wb, const float* __restrict__ bias) {
  constexpr int HO = HIN - 2;
  constexpr int NPH = CIN / 32;
  constexpr int NF = COUT / 16;
  constexpr int TX = 18;
  constexpr int SLOTS = TX * TX * 4;
  constexpr int ITERS = (SLOTS + 255) / 256;
  constexpr int ROWSTRIDE = TX * 4 * 16;
  __shared__ char lds[ITERS * 256 * 16];

  const int zb = blockIdx.z;
  const __hip_bfloat16* ip = in + (size_t)zb * HIN * HIN * CIN;
  __hip_bfloat16* op = out + (size_t)zb * HO * HO * COUT;
  const int lane = threadIdx.x & 63;
  const int wave = threadIdx.x >> 6;
  const int x0 = blockIdx.x * 16;
  const int y0 = blockIdx.y * 16;

  int abase[3];
#pragma unroll
  for (int kx = 0; kx < 3; ++kx) {
    int x = (lane & 15) + kx;
    int slot = (lane >> 4) ^ swz4(x);
    abase[kx] = (x * 4 + slot) * 16 + wave * 4 * ROWSTRIDE;
  }

  float bv[NF];
#pragma unroll
  for (int n = 0; n < NF; ++n) bv[n] = bias[n * 16 + (lane & 15)];
  float4_t acc[4][NF];
#pragma unroll
  for (int m = 0; m < 4; ++m)
#pragma unroll
    for (int n = 0; n < NF; ++n) acc[m][n] = {bv[n], bv[n], bv[n], bv[n]};

#pragma unroll
  for (int ph = 0; ph < NPH; ++ph) {
#pragma unroll
    for (int i = 0; i < ITERS; ++i) {
      int sbase = i * 256 + wave * 64;
      int slot = sbase + lane;
      slot = slot < SLOTS ? slot : SLOTS - 1;
      int pix = slot >> 2, scb = slot & 3;
      int y = pix / TX, x = pix - y * TX;
      int cb = scb ^ swz4(x);
      int gy = min(y0 + y, HIN - 1), gx = min(x0 + x, HIN - 1);
      const __hip_bfloat16* src = ip + ((size_t)gy * HIN + gx) * CIN + ph * 32 + cb * 8;
      gld16(src, lds + (size_t)sbase * 16);
    }
    __syncthreads();

#pragma unroll
    for (int t = 0; t < 9; ++t) {
      const int ky = t / 3, kx = t % 3;
      short8_t B[NF];
#pragma unroll
      for (int n = 0; n < NF; ++n)
        B[n] = *reinterpret_cast<const short8_t*>(
            wb + (size_t)(((t * NPH + ph) * NF + n) * 64 + lane) * 8);
#pragma unroll
      for (int m = 0; m < 4; ++m) {
        short8_t A = *reinterpret_cast<const short8_t*>(
            lds + abase[kx] + (m + ky) * ROWSTRIDE);
#pragma unroll
        for (int n = 0; n < NF; ++n)
          acc[m][n] = __builtin_amdgcn_mfma_f32_16x16x32_bf16(A, B[n], acc[m][n], 0, 0, 0);
      }
    }
    if (ph + 1 < NPH) __syncthreads();
  }

#pragma unroll
  for (int m = 0; m < 4; ++m) {
    int yy = y0 + wave * 4 + m;
    if (yy < HO) {
#pragma unroll
      for (int r = 0; r < 4; ++r) {
        int xx = x0 + (lane >> 4) * 4 + r;
        if (xx < HO) {
#pragma unroll
          for (int n = 0; n < NF; ++n) {
            float v = acc[m][n][r];
            v = v > 0.0f ? v : 0.0f;
            op[((size_t)yy * HO + xx) * COUT + n * 16 + (lane & 15)] = __float2bfloat16(v);
          }
        }
      }
    }
  }
}

// ---------------- conv4: 3x3 32->16 MFMA + sigmoid + pixel_shuffle(r=4) ----------------
__global__ __launch_bounds__(256, 4) void conv4_mfma(
    const __hip_bfloat16* __restrict__ in, float* __restrict__ out,
    const __hip_bfloat16* __restrict__ wb, const float* __restrict__ bias, int bBase) {
  constexpr int CIN = 32, HIN = HO3;
  constexpr int TX = 18;
  constexpr int SLOTS = TX * TX * 4;
  constexpr int ITERS = (SLOTS + 255) / 256;
  constexpr int ROWSTRIDE = TX * 4 * 16;
  __shared__ char lds[ITERS * 256 * 16];

  const int zb = blockIdx.z;
  const __hip_bfloat16* ip = in + (size_t)zb * HIN * HIN * CIN;
  const int lane = threadIdx.x & 63;
  const int wave = threadIdx.x >> 6;
  const int x0 = blockIdx.x * 16;
  const int y0 = blockIdx.y * 16;

#pragma unroll
  for (int i = 0; i < ITERS; ++i) {
    int sbase = i * 256 + wave * 64;
    int slot = sbase + lane;
    slot = slot < SLOTS ? slot : SLOTS - 1;
    int pix = slot >> 2, scb = slot & 3;
    int y = pix / TX, x = pix - y * TX;
    int cb = scb ^ swz4(x);
    int gy = min(y0 + y, HIN - 1), gx = min(x0 + x, HIN - 1);
    const __hip_bfloat16* src = ip + ((size_t)gy * HIN + gx) * CIN + cb * 8;
    gld16(src, lds + (size_t)sbase * 16);
  }
  __syncthreads();

  int abase[3];
#pragma unroll
  for (int kx = 0; kx < 3; ++kx) {
    int x = (lane & 15) + kx;
    int slot = (lane >> 4) ^ swz4(x);
    abase[kx] = (x * 4 + slot) * 16 + wave * 4 * ROWSTRIDE;
  }

  float bv = bias[lane & 15];
  float4_t acc[4];
#pragma unroll
  for (int m = 0; m < 4; ++m) acc[m] = {bv, bv, bv, bv};

#pragma unroll
  for (int t = 0; t < 9; ++t) {
    const int ky = t / 3, kx = t % 3;
    short8_t B = *reinterpret_cast<const short8_t*>(wb + (size_t)(t * 64 + lane) * 8);
#pragma unroll
    for (int m = 0; m < 4; ++m) {
      short8_t A = *reinterpret_cast<const short8_t*>(
          lds + abase[kx] + (m + ky) * ROWSTRIDE);
      acc[m] = __builtin_amdgcn_mfma_f32_16x16x32_bf16(A, B, acc[m], 0, 0, 0);
    }
  }
  float* ob = out + (size_t)(bBase + zb) * 1024 * 1024;
  const int oc = lane & 15;
#pragma unroll
  for (int m = 0; m < 4; ++m) {
    int yy = y0 + wave * 4 + m;
#pragma unroll
    for (int r = 0; r < 4; ++r) {
      int xx = x0 + (lane >> 4) * 4 + r;
      float v = 1.0f / (1.0f + expf(-acc[m][r]));
      ob[(size_t)(yy * 4 + (oc >> 2)) * 1024 + xx * 4 + (oc & 3)] = v;
    }
  }
}

extern "C" void kernel_launch(void* const* d_in, const int* in_sizes, int n_in,
                              void* d_out, int out_size, void* d_ws, size_t ws_size,
                              hipStream_t stream) {
  const float* x  = (const float*)d_in[0];
  const float* W1 = (const float*)d_in[1];
  const float* b1 = (const float*)d_in[2];
  const float* W2 = (const float*)d_in[3];
  const float* b2 = (const float*)d_in[4];
  const float* W3 = (const float*)d_in[5];
  const float* b3 = (const float*)d_in[6];
  const float* W4 = (const float*)d_in[7];
  const float* b4 = (const float*)d_in[8];
  float* out = (float*)d_out;

  __hip_bfloat16* wr1 = (__hip_bfloat16*)d_ws;   // 2048 elems
  __hip_bfloat16* wr2 = wr1 + 2048;              // 18432
  __hip_bfloat16* wr3 = wr2 + 18432;             // 9216
  __hip_bfloat16* wr4 = wr3 + 9216;              // 4608
  char* base = (char*)d_ws + 131072;

  const size_t xp_sz = (size_t)WPD * WPD * sizeof(float);
  const size_t h2_sz = (size_t)HO2 * HO2 * 32 * sizeof(__hip_bfloat16);
  const size_t h3_sz = (size_t)HO3 * HO3 * 32 * sizeof(__hip_bfloat16);
  const size_t per_b = xp_sz + h2_sz + h3_sz;    // ~8.87 MB/batch

  int g = (int)((ws_size - 131072) / per_b);
  if (g > 16) g = 16;
  if (g < 1) g = 1;

  float* xp = (float*)base;
  __hip_bfloat16* h2 = (__hip_bfloat16*)(base + (size_t)g * xp_sz);
  __hip_bfloat16* h3 = (__hip_bfloat16*)((char*)h2 + (size_t)g * h2_sz);

  repack_w1<<<8, 256, 0, stream>>>(W1, wr1);
  repack_w<<<72, 256, 0, stream>>>(W2, wr2, 64, 32);
  repack_w<<<36, 256, 0, stream>>>(W3, wr3, 32, 32);
  repack_w<<<18, 256, 0, stream>>>(W4, wr4, 32, 16);

  for (int bBase = 0; bBase < 16; bBase += g) {
    int gc = min(g, 16 - bBase);
    size_t tot = (size_t)gc * WPD * WPD;
    int fillBlocks = (int)min((tot + 255) / 256, (size_t)2048);
    pad_fill_kernel<<<fillBlocks, 256, 0, stream>>>(x, xp, bBase, gc);
    extrap_kernel<<<gc, 256, 0, stream>>>(xp);
    conv12_mfma<<<dim3(17, 17, gc), 256, 0, stream>>>(xp, h2, wr1, b1, wr2, b2);
    conv3x3_mfma<32, 32, HO2><<<dim3(17, 17, gc), 256, 0, stream>>>(h2, h3, wr3, b3);
    conv4_mfma<<<dim3(16, 16, gc), 256, 0, stream>>>(h3, out, wr4, b4, bBase);
  }
}

// Round 8
// 211.920 us; speedup vs baseline: 7.6246x; 1.0991x over previous
//
#include <hip/hip_runtime.h>
#include <hip/hip_bf16.h>
#include <math.h>

// Geometry
#define WPD 266   // padded H=W
#define HO1 262   // after 5x5 (virtual; h1 lives only in LDS)
#define HO2 260
#define HO3 258
#define HO4 256

typedef __attribute__((ext_vector_type(8))) short short8_t;
typedef __attribute__((ext_vector_type(4))) float float4_t;

__device__ inline void gld16(const void* g, void* l) {
  __builtin_amdgcn_global_load_lds(
      (const __attribute__((address_space(1))) void*)g,
      (__attribute__((address_space(3))) void*)l, 16, 0, 0);
}

// ---------------- pad fill: xp = pad(x, 5, value=0.5) ----------------
__global__ void pad_fill_kernel(const float* __restrict__ x, float* __restrict__ xp,
                                int bBase, int gc) {
  size_t total = (size_t)gc * WPD * WPD;
  for (size_t idx = (size_t)blockIdx.x * blockDim.x + threadIdx.x; idx < total;
       idx += (size_t)gridDim.x * blockDim.x) {
    size_t zb = idx / (WPD * WPD);
    int rem = (int)(idx % (WPD * WPD));
    int y = rem / WPD, xx = rem % WPD;
    float v = 0.5f;
    if (y >= 5 && y < 261 && xx >= 5 && xx < 261)
      v = x[((size_t)(bBase + zb) * 256 + (y - 5)) * 256 + (xx - 5)];
    xp[idx] = v;
  }
}

// ---------------- border extrapolation (sequential rings i=5..1) ----------------
__global__ void extrap_kernel(float* __restrict__ xp) {
  const int W = WPD, H = WPD;
  float* p = xp + (size_t)blockIdx.x * W * W;
  for (int i = 5; i >= 1; --i) {
    int ip = i + 1, im = i - 1;
    int L = W - 2 * ip;
    for (int t = threadIdx.x; t < 4 * L; t += blockDim.x) {
      int e = t / L, j = t % L;
      float a;
      if (e == 0) {
        a = (p[i * W + i + j] + p[i * W + i + j + 1] + p[i * W + i + j + 2]) / 3.0f;
        p[im * W + ip + j] = a > 0.3f ? 1.0f : a;
      } else if (e == 1) {
        const float* r = p + (H - ip) * W;
        a = (r[i + j] + r[i + j + 1] + r[i + j + 2]) / 3.0f;
        p[(H - i) * W + ip + j] = a > 0.3f ? 1.0f : a;
      } else if (e == 2) {
        a = (p[(i + j) * W + i] + p[(i + j + 1) * W + i] + p[(i + j + 2) * W + i]) / 3.0f;
        p[(ip + j) * W + im] = a > 0.3f ? 1.0f : a;
      } else {
        a = (p[(i + j) * W + (W - ip)] + p[(i + j + 1) * W + (W - ip)] +
             p[(i + j + 2) * W + (W - ip)]) / 3.0f;
        p[(ip + j) * W + (W - i)] = a > 0.3f ? 1.0f : a;
      }
    }
    __syncthreads();
    if (threadIdx.x < 4) {
      int c = threadIdx.x;
      int cx, cy, nx, ny;
      if (c == 0)      { cx = im;    cy = im;    nx = 1;  ny = 1;  }
      else if (c == 1) { cx = W - i; cy = im;    nx = -1; ny = 1;  }
      else if (c == 2) { cx = W - i; cy = H - i; nx = -1; ny = -1; }
      else             { cx = im;    cy = H - i; nx = 1;  ny = -1; }
      int cxp = cx + nx, cyp = cy + ny;
      p[cy * W + cxp] = (p[cyp * W + cxp] + p[cy * W + cx + 2 * nx]) * 0.5f;
      p[cyp * W + cx] = (p[cyp * W + cxp] + p[(cy + 2 * ny) * W + cx]) * 0.5f;
      p[cy * W + cx]  = (p[cy * W + cxp] + p[cyp * W + cx]) * 0.5f;
    }
    __syncthreads();
  }
}

// ---------------- conv1 weight repack: Wr[n][lane][j] = W1[oc][tap], tap>=25 -> 0 ----
__global__ void repack_w1(const float* __restrict__ W, __hip_bfloat16* __restrict__ Wr) {
  int idx = blockIdx.x * blockDim.x + threadIdx.x;
  if (idx < 2048) {
    int j = idx & 7, l = (idx >> 3) & 63, n = idx >> 9;
    int oc = n * 16 + (l & 15);
    int tap = (l >> 4) * 8 + j;
    Wr[idx] = __float2bfloat16(tap < 25 ? W[oc * 25 + tap] : 0.0f);
  }
}

// ---------------- weight repack for MFMA B-fragments (3x3 convs) ----------------
__global__ void repack_w(const float* __restrict__ W, __hip_bfloat16* __restrict__ Wr,
                         int CIN, int COUT) {
  int NC = CIN / 32, NF = COUT / 16;
  int total = 9 * NC * NF * 512;
  for (int idx = blockIdx.x * blockDim.x + threadIdx.x; idx < total;
       idx += gridDim.x * blockDim.x) {
    int j = idx & 7, l = (idx >> 3) & 63;
    int rest = idx >> 9;
    int n = rest % NF; rest /= NF;
    int c = rest % NC; int t = rest / NC;
    int oc = n * 16 + (l & 15);
    int ic = c * 32 + (l >> 4) * 8 + j;
    Wr[idx] = __float2bfloat16(W[((size_t)oc * CIN + ic) * 9 + t]);
  }
}

// involutive bank-spreading swizzle of the 4-chunk index by tile-local x
__device__ inline int swz4(int x) { return (x & 3) ^ ((x >> 2) & 3); }

// ---------------- fused conv1(5x5,1->64)+conv2(3x3,64->32): h1 stays in LDS ----
// Spill-free restructure: conv1 MFMA -> immediate lds2 store per mi (8 live
// regs instead of 48), A-fragments hoisted (phase-invariant), register budget
// pinned to 128 via amdgpu_waves_per_eu(4,4).
__global__ __launch_bounds__(256)
__attribute__((amdgpu_waves_per_eu(4, 4)))
void conv12_mfma(
    const float* __restrict__ xp, __hip_bfloat16* __restrict__ h2,
    const __hip_bfloat16* __restrict__ w1r, const float* __restrict__ b1,
    const __hip_bfloat16* __restrict__ w2r, const float* __restrict__ b2) {
  const int HIN = WPD;        // xp 266
  const int HO = HO2;         // 260
  const int zb = blockIdx.z;
  const float* p = xp + (size_t)zb * HIN * HIN;
  const int x0 = blockIdx.x * 16, y0 = blockIdx.y * 16;
  const int lane = threadIdx.x & 63;
  const int wave = threadIdx.x >> 6;
  const int lx = lane & 15, kg = lane >> 4;

  __shared__ short lds1[26 * 22];   // rows 0..21 xp data, 22..25 zeros
  __shared__ char lds2[18 * 1152];  // 18x18 x 32ch bf16, chunk-swizzled

  // ---- stage xp patch (f32 -> bf16), zero pad rows ----
  for (int idx = threadIdx.x; idx < 26 * 22; idx += 256) {
    int r = idx / 22, c = idx % 22;
    short v = 0;
    if (r < 22) {
      int yy = min(y0 + r, HIN - 1), xx = min(x0 + c, HIN - 1);
      __hip_bfloat16 h = __float2bfloat16(p[yy * HIN + xx]);
      v = *reinterpret_cast<short*>(&h);
    }
    lds1[idx] = v;
  }

  // conv1 tap offsets (lane-dependent, phase-independent)
  int toff[8]; bool tvalid[8];
#pragma unroll
  for (int j = 0; j < 8; ++j) {
    int tap = kg * 8 + j;
    int ky = tap / 5, kx = tap - ky * 5;
    tvalid[j] = tap < 25;
    toff[j] = ky * 22 + kx;
  }
  // conv2 A-fragment byte bases (per kx)
  int abase[3];
#pragma unroll
  for (int kx = 0; kx < 3; ++kx) {
    int x = lx + kx;
    int slot = kg ^ swz4(x);
    abase[kx] = (x * 4 + slot) * 16 + wave * 4 * 1152;
  }

  float bv2[2];
#pragma unroll
  for (int n = 0; n < 2; ++n) bv2[n] = b2[n * 16 + lx];
  float4_t acc2[4][2];
#pragma unroll
  for (int m = 0; m < 4; ++m)
#pragma unroll
    for (int n = 0; n < 2; ++n) acc2[m][n] = {bv2[n], bv2[n], bv2[n], bv2[n]};

  __syncthreads();  // lds1 ready

  // ---- hoist conv1 A-fragments (phase-invariant): 6 x short8 = 24 VGPR ----
  short8_t Af[6];
#pragma unroll
  for (int mi = 0; mi < 6; ++mi) {
    int pp = mi * 64 + wave * 16 + lx;
    pp = pp < 324 ? pp : 323;
    int y1 = pp / 18, x1 = pp - y1 * 18;
    int bs = y1 * 22 + x1;
#pragma unroll
    for (int j = 0; j < 8; ++j)
      Af[mi][j] = lds1[tvalid[j] ? bs + toff[j] : 484 + lx];
  }

#pragma unroll
  for (int ph = 0; ph < 2; ++ph) {
    short8_t B1[2];
    float bb[2];
#pragma unroll
    for (int n2 = 0; n2 < 2; ++n2) {
      B1[n2] = *reinterpret_cast<const short8_t*>(
          w1r + (size_t)((ph * 2 + n2) * 64 + lane) * 8);
      bb[n2] = b1[(ph * 2 + n2) * 16 + lx];
    }
    if (ph) __syncthreads();  // previous conv2 phase done reading lds2

    // ---- conv1: MFMA + immediate relu/bf16 store into swizzled lds2 ----
#pragma unroll
    for (int mi = 0; mi < 6; ++mi) {
      int pb = mi * 64 + wave * 16;
      if (pb < 324) {
        float4_t a0 = {bb[0], bb[0], bb[0], bb[0]};
        float4_t a1 = {bb[1], bb[1], bb[1], bb[1]};
        a0 = __builtin_amdgcn_mfma_f32_16x16x32_bf16(Af[mi], B1[0], a0, 0, 0, 0);
        a1 = __builtin_amdgcn_mfma_f32_16x16x32_bf16(Af[mi], B1[1], a1, 0, 0, 0);
#pragma unroll
        for (int r = 0; r < 4; ++r) {
          int pd = pb + kg * 4 + r;
          if (pd < 324) {
            int y2 = pd / 18, x2 = pd - y2 * 18;
            {
              int cb = 0 * 2 + (lx >> 3);
              int slot = cb ^ swz4(x2);
              float v = a0[r] > 0.0f ? a0[r] : 0.0f;
              __hip_bfloat16 h = __float2bfloat16(v);
              *reinterpret_cast<short*>(lds2 + y2 * 1152 + (x2 * 4 + slot) * 16 +
                                        (lx & 7) * 2) = *reinterpret_cast<short*>(&h);
            }
            {
              int cb = 1 * 2 + (lx >> 3);
              int slot = cb ^ swz4(x2);
              float v = a1[r] > 0.0f ? a1[r] : 0.0f;
              __hip_bfloat16 h = __float2bfloat16(v);
              *reinterpret_cast<short*>(lds2 + y2 * 1152 + (x2 * 4 + slot) * 16 +
                                        (lx & 7) * 2) = *reinterpret_cast<short*>(&h);
            }
          }
        }
      }
    }
    __syncthreads();  // lds2 ready

    // ---- conv2 phase: 9-tap MFMA over lds2 ----
#pragma unroll
    for (int t = 0; t < 9; ++t) {
      const int ky = t / 3, kx = t % 3;
      short8_t B2[2];
#pragma unroll
      for (int n = 0; n < 2; ++n)
        B2[n] = *reinterpret_cast<const short8_t*>(
            w2r + (size_t)(((t * 2 + ph) * 2 + n) * 64 + lane) * 8);
#pragma unroll
      for (int m = 0; m < 4; ++m) {
        short8_t A = *reinterpret_cast<const short8_t*>(lds2 + abase[kx] + (m + ky) * 1152);
#pragma unroll
        for (int n = 0; n < 2; ++n)
          acc2[m][n] = __builtin_amdgcn_mfma_f32_16x16x32_bf16(A, B2[n], acc2[m][n], 0, 0, 0);
      }
    }
  }

  // ---- epilogue: relu + NHWC bf16 store of h2 ----
  __hip_bfloat16* op = h2 + (size_t)zb * HO * HO * 32;
#pragma unroll
  for (int m = 0; m < 4; ++m) {
    int yy = y0 + wave * 4 + m;
    if (yy < HO) {
#pragma unroll
      for (int r = 0; r < 4; ++r) {
        int xx = x0 + kg * 4 + r;
        if (xx < HO) {
#pragma unroll
          for (int n = 0; n < 2; ++n) {
            float v = acc2[m][n][r];
            v = v > 0.0f ? v : 0.0f;
            op[((size_t)yy * HO + xx) * 32 + n * 16 + lx] = __float2bfloat16(v);
          }
        }
      }
    }
  }
}

// ---------------- 3x3 conv via MFMA implicit GEMM + LDS-staged A ----------------
template <int CIN, int COUT, int HIN>
__global__ __launch_bounds__(256, 4) void conv3x3_mfma(
    const __hip_bfloat16* __restrict__ in, __hip_bfloat16* __restrict__ out,
    const __hip_bfloat16* __restrict__ wb, const float* __restrict__ bias) {
  constexpr int HO = HIN - 2;
  constexpr int NPH = CIN / 32;
  constexpr int NF = COUT / 16;
  constexpr int TX = 18;
  constexpr int SLOTS = TX * TX * 4;
  constexpr int ITERS = (SLOTS + 255) / 256;
  constexpr int ROWSTRIDE = TX * 4 * 16;
  __shared__ char lds[ITERS * 256 * 16];

  const int zb = blockIdx.z;
  const __hip_bfloat16* ip = in + (size_t)zb * HIN * HIN * CIN;
  __hip_bfloat16* op = out + (size_t)zb * HO * HO * COUT;
  const int lane = threadIdx.x & 63;
  const int wave = threadIdx.x >> 6;
  const int x0 = blockIdx.x * 16;
  const int y0 = blockIdx.y * 16;

  int abase[3];
#pragma unroll
  for (int kx = 0; kx < 3; ++kx) {
    int x = (lane & 15) + kx;
    int slot = (lane >> 4) ^ swz4(x);
    abase[kx] = (x * 4 + slot) * 16 + wave * 4 * ROWSTRIDE;
  }

  float bv[NF];
#pragma unroll
  for (int n = 0; n < NF; ++n) bv[n] = bias[n * 16 + (lane & 15)];
  float4_t acc[4][NF];
#pragma unroll
  for (int m = 0; m < 4; ++m)
#pragma unroll
    for (int n = 0; n < NF; ++n) acc[m][n] = {bv[n], bv[n], bv[n], bv[n]};

#pragma unroll
  for (int ph = 0; ph < NPH; ++ph) {
#pragma unroll
    for (int i = 0; i < ITERS; ++i) {
      int sbase = i * 256 + wave * 64;
      int slot = sbase + lane;
      slot = slot < SLOTS ? slot : SLOTS - 1;
      int pix = slot >> 2, scb = slot & 3;
      int y = pix / TX, x = pix - y * TX;
      int cb = scb ^ swz4(x);
      int gy = min(y0 + y, HIN - 1), gx = min(x0 + x, HIN - 1);
      const __hip_bfloat16* src = ip + ((size_t)gy * HIN + gx) * CIN + ph * 32 + cb * 8;
      gld16(src, lds + (size_t)sbase * 16);
    }
    __syncthreads();

#pragma unroll
    for (int t = 0; t < 9; ++t) {
      const int ky = t / 3, kx = t % 3;
      short8_t B[NF];
#pragma unroll
      for (int n = 0; n < NF; ++n)
        B[n] = *reinterpret_cast<const short8_t*>(
            wb + (size_t)(((t * NPH + ph) * NF + n) * 64 + lane) * 8);
#pragma unroll
      for (int m = 0; m < 4; ++m) {
        short8_t A = *reinterpret_cast<const short8_t*>(
            lds + abase[kx] + (m + ky) * ROWSTRIDE);
#pragma unroll
        for (int n = 0; n < NF; ++n)
          acc[m][n] = __builtin_amdgcn_mfma_f32_16x16x32_bf16(A, B[n], acc[m][n], 0, 0, 0);
      }
    }
    if (ph + 1 < NPH) __syncthreads();
  }

#pragma unroll
  for (int m = 0; m < 4; ++m) {
    int yy = y0 + wave * 4 + m;
    if (yy < HO) {
#pragma unroll
      for (int r = 0; r < 4; ++r) {
        int xx = x0 + (lane >> 4) * 4 + r;
        if (xx < HO) {
#pragma unroll
          for (int n = 0; n < NF; ++n) {
            float v = acc[m][n][r];
            v = v > 0.0f ? v : 0.0f;
            op[((size_t)yy * HO + xx) * COUT + n * 16 + (lane & 15)] = __float2bfloat16(v);
          }
        }
      }
    }
  }
}

// ---------------- conv4: 3x3 32->16 MFMA + sigmoid + pixel_shuffle(r=4) ----------------
__global__ __launch_bounds__(256, 4) void conv4_mfma(
    const __hip_bfloat16* __restrict__ in, float* __restrict__ out,
    const __hip_bfloat16* __restrict__ wb, const float* __restrict__ bias, int bBase) {
  constexpr int CIN = 32, HIN = HO3;
  constexpr int TX = 18;
  constexpr int SLOTS = TX * TX * 4;
  constexpr int ITERS = (SLOTS + 255) / 256;
  constexpr int ROWSTRIDE = TX * 4 * 16;
  __shared__ char lds[ITERS * 256 * 16];

  const int zb = blockIdx.z;
  const __hip_bfloat16* ip = in + (size_t)zb * HIN * HIN * CIN;
  const int lane = threadIdx.x & 63;
  const int wave = threadIdx.x >> 6;
  const int x0 = blockIdx.x * 16;
  const int y0 = blockIdx.y * 16;

#pragma unroll
  for (int i = 0; i < ITERS; ++i) {
    int sbase = i * 256 + wave * 64;
    int slot = sbase + lane;
    slot = slot < SLOTS ? slot : SLOTS - 1;
    int pix = slot >> 2, scb = slot & 3;
    int y = pix / TX, x = pix - y * TX;
    int cb = scb ^ swz4(x);
    int gy = min(y0 + y, HIN - 1), gx = min(x0 + x, HIN - 1);
    const __hip_bfloat16* src = ip + ((size_t)gy * HIN + gx) * CIN + cb * 8;
    gld16(src, lds + (size_t)sbase * 16);
  }
  __syncthreads();

  int abase[3];
#pragma unroll
  for (int kx = 0; kx < 3; ++kx) {
    int x = (lane & 15) + kx;
    int slot = (lane >> 4) ^ swz4(x);
    abase[kx] = (x * 4 + slot) * 16 + wave * 4 * ROWSTRIDE;
  }

  float bv = bias[lane & 15];
  float4_t acc[4];
#pragma unroll
  for (int m = 0; m < 4; ++m) acc[m] = {bv, bv, bv, bv};

#pragma unroll
  for (int t = 0; t < 9; ++t) {
    const int ky = t / 3, kx = t % 3;
    short8_t B = *reinterpret_cast<const short8_t*>(wb + (size_t)(t * 64 + lane) * 8);
#pragma unroll
    for (int m = 0; m < 4; ++m) {
      short8_t A = *reinterpret_cast<const short8_t*>(
          lds + abase[kx] + (m + ky) * ROWSTRIDE);
      acc[m] = __builtin_amdgcn_mfma_f32_16x16x32_bf16(A, B, acc[m], 0, 0, 0);
    }
  }
  float* ob = out + (size_t)(bBase + zb) * 1024 * 1024;
  const int oc = lane & 15;
#pragma unroll
  for (int m = 0; m < 4; ++m) {
    int yy = y0 + wave * 4 + m;
#pragma unroll
    for (int r = 0; r < 4; ++r) {
      int xx = x0 + (lane >> 4) * 4 + r;
      float v = 1.0f / (1.0f + expf(-acc[m][r]));
      ob[(size_t)(yy * 4 + (oc >> 2)) * 1024 + xx * 4 + (oc & 3)] = v;
    }
  }
}

extern "C" void kernel_launch(void* const* d_in, const int* in_sizes, int n_in,
                              void* d_out, int out_size, void* d_ws, size_t ws_size,
                              hipStream_t stream) {
  const float* x  = (const float*)d_in[0];
  const float* W1 = (const float*)d_in[1];
  const float* b1 = (const float*)d_in[2];
  const float* W2 = (const float*)d_in[3];
  const float* b2 = (const float*)d_in[4];
  const float* W3 = (const float*)d_in[5];
  const float* b3 = (const float*)d_in[6];
  const float* W4 = (const float*)d_in[7];
  const float* b4 = (const float*)d_in[8];
  float* out = (float*)d_out;

  __hip_bfloat16* wr1 = (__hip_bfloat16*)d_ws;   // 2048 elems
  __hip_bfloat16* wr2 = wr1 + 2048;              // 18432
  __hip_bfloat16* wr3 = wr2 + 18432;             // 9216
  __hip_bfloat16* wr4 = wr3 + 9216;              // 4608
  char* base = (char*)d_ws + 131072;

  const size_t xp_sz = (size_t)WPD * WPD * sizeof(float);
  const size_t h2_sz = (size_t)HO2 * HO2 * 32 * sizeof(__hip_bfloat16);
  const size_t h3_sz = (size_t)HO3 * HO3 * 32 * sizeof(__hip_bfloat16);
  const size_t per_b = xp_sz + h2_sz + h3_sz;    // ~8.87 MB/batch

  int g = (int)((ws_size - 131072) / per_b);
  if (g > 16) g = 16;
  if (g < 1) g = 1;

  float* xp = (float*)base;
  __hip_bfloat16* h2 = (__hip_bfloat16*)(base + (size_t)g * xp_sz);
  __hip_bfloat16* h3 = (__hip_bfloat16*)((char*)h2 + (size_t)g * h2_sz);

  repack_w1<<<8, 256, 0, stream>>>(W1, wr1);
  repack_w<<<72, 256, 0, stream>>>(W2, wr2, 64, 32);
  repack_w<<<36, 256, 0, stream>>>(W3, wr3, 32, 32);
  repack_w<<<18, 256, 0, stream>>>(W4, wr4, 32, 16);

  for (int bBase = 0; bBase < 16; bBase += g) {
    int gc = min(g, 16 - bBase);
    size_t tot = (size_t)gc * WPD * WPD;
    int fillBlocks = (int)min((tot + 255) / 256, (size_t)2048);
    pad_fill_kernel<<<fillBlocks, 256, 0, stream>>>(x, xp, bBase, gc);
    extrap_kernel<<<gc, 256, 0, stream>>>(xp);
    conv12_mfma<<<dim3(17, 17, gc), 256, 0, stream>>>(xp, h2, wr1, b1, wr2, b2);
    conv3x3_mfma<32, 32, HO2><<<dim3(17, 17, gc), 256, 0, stream>>>(h2, h3, wr3, b3);
    conv4_mfma<<<dim3(16, 16, gc), 256, 0, stream>>>(h3, out, wr4, b4, bBase);
  }
}

// Round 9
// 185.095 us; speedup vs baseline: 8.7295x; 1.1449x over previous
//
#include <hip/hip_runtime.h>
#include <hip/hip_bf16.h>
#include <math.h>

// Geometry
#define WPD 266   // padded H=W
#define HO1 262   // after 5x5 (virtual; h1 lives only in LDS)
#define HO2 260
#define HO3 258
#define HO4 256

typedef __attribute__((ext_vector_type(8))) short short8_t;
typedef __attribute__((ext_vector_type(4))) float float4_t;

__device__ inline void gld16(const void* g, void* l) {
  __builtin_amdgcn_global_load_lds(
      (const __attribute__((address_space(1))) void*)g,
      (__attribute__((address_space(3))) void*)l, 16, 0, 0);
}

// ---------------- pad fill: xp = pad(x, 5, value=0.5) ----------------
__global__ void pad_fill_kernel(const float* __restrict__ x, float* __restrict__ xp,
                                int bBase, int gc) {
  size_t total = (size_t)gc * WPD * WPD;
  for (size_t idx = (size_t)blockIdx.x * blockDim.x + threadIdx.x; idx < total;
       idx += (size_t)gridDim.x * blockDim.x) {
    size_t zb = idx / (WPD * WPD);
    int rem = (int)(idx % (WPD * WPD));
    int y = rem / WPD, xx = rem % WPD;
    float v = 0.5f;
    if (y >= 5 && y < 261 && xx >= 5 && xx < 261)
      v = x[((size_t)(bBase + zb) * 256 + (y - 5)) * 256 + (xx - 5)];
    xp[idx] = v;
  }
}

// ---------------- border extrapolation (sequential rings i=5..1) ----------------
__global__ void extrap_kernel(float* __restrict__ xp) {
  const int W = WPD, H = WPD;
  float* p = xp + (size_t)blockIdx.x * W * W;
  for (int i = 5; i >= 1; --i) {
    int ip = i + 1, im = i - 1;
    int L = W - 2 * ip;
    for (int t = threadIdx.x; t < 4 * L; t += blockDim.x) {
      int e = t / L, j = t % L;
      float a;
      if (e == 0) {
        a = (p[i * W + i + j] + p[i * W + i + j + 1] + p[i * W + i + j + 2]) / 3.0f;
        p[im * W + ip + j] = a > 0.3f ? 1.0f : a;
      } else if (e == 1) {
        const float* r = p + (H - ip) * W;
        a = (r[i + j] + r[i + j + 1] + r[i + j + 2]) / 3.0f;
        p[(H - i) * W + ip + j] = a > 0.3f ? 1.0f : a;
      } else if (e == 2) {
        a = (p[(i + j) * W + i] + p[(i + j + 1) * W + i] + p[(i + j + 2) * W + i]) / 3.0f;
        p[(ip + j) * W + im] = a > 0.3f ? 1.0f : a;
      } else {
        a = (p[(i + j) * W + (W - ip)] + p[(i + j + 1) * W + (W - ip)] +
             p[(i + j + 2) * W + (W - ip)]) / 3.0f;
        p[(ip + j) * W + (W - i)] = a > 0.3f ? 1.0f : a;
      }
    }
    __syncthreads();
    if (threadIdx.x < 4) {
      int c = threadIdx.x;
      int cx, cy, nx, ny;
      if (c == 0)      { cx = im;    cy = im;    nx = 1;  ny = 1;  }
      else if (c == 1) { cx = W - i; cy = im;    nx = -1; ny = 1;  }
      else if (c == 2) { cx = W - i; cy = H - i; nx = -1; ny = -1; }
      else             { cx = im;    cy = H - i; nx = 1;  ny = -1; }
      int cxp = cx + nx, cyp = cy + ny;
      p[cy * W + cxp] = (p[cyp * W + cxp] + p[cy * W + cx + 2 * nx]) * 0.5f;
      p[cyp * W + cx] = (p[cyp * W + cxp] + p[(cy + 2 * ny) * W + cx]) * 0.5f;
      p[cy * W + cx]  = (p[cy * W + cxp] + p[cyp * W + cx]) * 0.5f;
    }
    __syncthreads();
  }
}

// ---------------- conv1 weight repack: Wr[n][lane][j] = W1[oc][tap], tap>=25 -> 0 ----
__global__ void repack_w1(const float* __restrict__ W, __hip_bfloat16* __restrict__ Wr) {
  int idx = blockIdx.x * blockDim.x + threadIdx.x;
  if (idx < 2048) {
    int j = idx & 7, l = (idx >> 3) & 63, n = idx >> 9;
    int oc = n * 16 + (l & 15);
    int tap = (l >> 4) * 8 + j;
    Wr[idx] = __float2bfloat16(tap < 25 ? W[oc * 25 + tap] : 0.0f);
  }
}

// ---------------- weight repack for MFMA B-fragments (3x3 convs) ----------------
__global__ void repack_w(const float* __restrict__ W, __hip_bfloat16* __restrict__ Wr,
                         int CIN, int COUT) {
  int NC = CIN / 32, NF = COUT / 16;
  int total = 9 * NC * NF * 512;
  for (int idx = blockIdx.x * blockDim.x + threadIdx.x; idx < total;
       idx += gridDim.x * blockDim.x) {
    int j = idx & 7, l = (idx >> 3) & 63;
    int rest = idx >> 9;
    int n = rest % NF; rest /= NF;
    int c = rest % NC; int t = rest / NC;
    int oc = n * 16 + (l & 15);
    int ic = c * 32 + (l >> 4) * 8 + j;
    Wr[idx] = __float2bfloat16(W[((size_t)oc * CIN + ic) * 9 + t]);
  }
}

// involutive bank-spreading swizzle of the 4-chunk index by tile-local x
__device__ inline int swz4(int x) { return (x & 3) ^ ((x >> 2) & 3); }

// ---------------- fused conv1(5x5,1->64)+conv2(3x3,64->32): h1 stays in LDS ----
// __launch_bounds__(256, 2): min 2 waves/EU -> VGPR cap 256 -> no scratch spills.
// (R8's amdgpu_waves_per_eu(4,4) was ignored; VGPR stayed 64 and spill traffic
// dominated: WRITE 211MB vs 69MB ideal.)
__global__ __launch_bounds__(256, 2)
void conv12_mfma(
    const float* __restrict__ xp, __hip_bfloat16* __restrict__ h2,
    const __hip_bfloat16* __restrict__ w1r, const float* __restrict__ b1,
    const __hip_bfloat16* __restrict__ w2r, const float* __restrict__ b2) {
  const int HIN = WPD;        // xp 266
  const int HO = HO2;         // 260
  const int zb = blockIdx.z;
  const float* p = xp + (size_t)zb * HIN * HIN;
  const int x0 = blockIdx.x * 16, y0 = blockIdx.y * 16;
  const int lane = threadIdx.x & 63;
  const int wave = threadIdx.x >> 6;
  const int lx = lane & 15, kg = lane >> 4;

  __shared__ short lds1[26 * 22];   // rows 0..21 xp data, 22..25 zeros
  __shared__ char lds2[18 * 1152];  // 18x18 x 32ch bf16, chunk-swizzled

  // ---- stage xp patch (f32 -> bf16), zero pad rows ----
  for (int idx = threadIdx.x; idx < 26 * 22; idx += 256) {
    int r = idx / 22, c = idx % 22;
    short v = 0;
    if (r < 22) {
      int yy = min(y0 + r, HIN - 1), xx = min(x0 + c, HIN - 1);
      __hip_bfloat16 h = __float2bfloat16(p[yy * HIN + xx]);
      v = *reinterpret_cast<short*>(&h);
    }
    lds1[idx] = v;
  }

  // conv1 tap offsets (lane-dependent, phase-independent)
  int toff[8]; bool tvalid[8];
#pragma unroll
  for (int j = 0; j < 8; ++j) {
    int tap = kg * 8 + j;
    int ky = tap / 5, kx = tap - ky * 5;
    tvalid[j] = tap < 25;
    toff[j] = ky * 22 + kx;
  }
  // conv2 A-fragment byte bases (per kx)
  int abase[3];
#pragma unroll
  for (int kx = 0; kx < 3; ++kx) {
    int x = lx + kx;
    int slot = kg ^ swz4(x);
    abase[kx] = (x * 4 + slot) * 16 + wave * 4 * 1152;
  }

  float bv2[2];
#pragma unroll
  for (int n = 0; n < 2; ++n) bv2[n] = b2[n * 16 + lx];
  float4_t acc2[4][2];
#pragma unroll
  for (int m = 0; m < 4; ++m)
#pragma unroll
    for (int n = 0; n < 2; ++n) acc2[m][n] = {bv2[n], bv2[n], bv2[n], bv2[n]};

  __syncthreads();  // lds1 ready

  // ---- hoist conv1 A-fragments (phase-invariant): 6 x short8 = 24 VGPR ----
  short8_t Af[6];
#pragma unroll
  for (int mi = 0; mi < 6; ++mi) {
    int pp = mi * 64 + wave * 16 + lx;
    pp = pp < 324 ? pp : 323;
    int y1 = pp / 18, x1 = pp - y1 * 18;
    int bs = y1 * 22 + x1;
#pragma unroll
    for (int j = 0; j < 8; ++j)
      Af[mi][j] = lds1[tvalid[j] ? bs + toff[j] : 484 + lx];
  }

#pragma unroll
  for (int ph = 0; ph < 2; ++ph) {
    short8_t B1[2];
    float bb[2];
#pragma unroll
    for (int n2 = 0; n2 < 2; ++n2) {
      B1[n2] = *reinterpret_cast<const short8_t*>(
          w1r + (size_t)((ph * 2 + n2) * 64 + lane) * 8);
      bb[n2] = b1[(ph * 2 + n2) * 16 + lx];
    }
    if (ph) __syncthreads();  // previous conv2 phase done reading lds2

    // ---- conv1: MFMA + immediate relu/bf16 store into swizzled lds2 ----
#pragma unroll
    for (int mi = 0; mi < 6; ++mi) {
      int pb = mi * 64 + wave * 16;
      if (pb < 324) {
        float4_t a0 = {bb[0], bb[0], bb[0], bb[0]};
        float4_t a1 = {bb[1], bb[1], bb[1], bb[1]};
        a0 = __builtin_amdgcn_mfma_f32_16x16x32_bf16(Af[mi], B1[0], a0, 0, 0, 0);
        a1 = __builtin_amdgcn_mfma_f32_16x16x32_bf16(Af[mi], B1[1], a1, 0, 0, 0);
#pragma unroll
        for (int r = 0; r < 4; ++r) {
          int pd = pb + kg * 4 + r;
          if (pd < 324) {
            int y2 = pd / 18, x2 = pd - y2 * 18;
            {
              int cb = 0 * 2 + (lx >> 3);
              int slot = cb ^ swz4(x2);
              float v = a0[r] > 0.0f ? a0[r] : 0.0f;
              __hip_bfloat16 h = __float2bfloat16(v);
              *reinterpret_cast<short*>(lds2 + y2 * 1152 + (x2 * 4 + slot) * 16 +
                                        (lx & 7) * 2) = *reinterpret_cast<short*>(&h);
            }
            {
              int cb = 1 * 2 + (lx >> 3);
              int slot = cb ^ swz4(x2);
              float v = a1[r] > 0.0f ? a1[r] : 0.0f;
              __hip_bfloat16 h = __float2bfloat16(v);
              *reinterpret_cast<short*>(lds2 + y2 * 1152 + (x2 * 4 + slot) * 16 +
                                        (lx & 7) * 2) = *reinterpret_cast<short*>(&h);
            }
          }
        }
      }
    }
    __syncthreads();  // lds2 ready

    // ---- conv2 phase: 9-tap MFMA over lds2 ----
#pragma unroll
    for (int t = 0; t < 9; ++t) {
      const int ky = t / 3, kx = t % 3;
      short8_t B2[2];
#pragma unroll
      for (int n = 0; n < 2; ++n)
        B2[n] = *reinterpret_cast<const short8_t*>(
            w2r + (size_t)(((t * 2 + ph) * 2 + n) * 64 + lane) * 8);
#pragma unroll
      for (int m = 0; m < 4; ++m) {
        short8_t A = *reinterpret_cast<const short8_t*>(lds2 + abase[kx] + (m + ky) * 1152);
#pragma unroll
        for (int n = 0; n < 2; ++n)
          acc2[m][n] = __builtin_amdgcn_mfma_f32_16x16x32_bf16(A, B2[n], acc2[m][n], 0, 0, 0);
      }
    }
  }

  // ---- epilogue: relu + NHWC bf16 store of h2 ----
  __hip_bfloat16* op = h2 + (size_t)zb * HO * HO * 32;
#pragma unroll
  for (int m = 0; m < 4; ++m) {
    int yy = y0 + wave * 4 + m;
    if (yy < HO) {
#pragma unroll
      for (int r = 0; r < 4; ++r) {
        int xx = x0 + kg * 4 + r;
        if (xx < HO) {
#pragma unroll
          for (int n = 0; n < 2; ++n) {
            float v = acc2[m][n][r];
            v = v > 0.0f ? v : 0.0f;
            op[((size_t)yy * HO + xx) * 32 + n * 16 + lx] = __float2bfloat16(v);
          }
        }
      }
    }
  }
}

// ---------------- 3x3 conv via MFMA implicit GEMM + LDS-staged A ----------------
template <int CIN, int COUT, int HIN>
__global__ __launch_bounds__(256, 4) void conv3x3_mfma(
    const __hip_bfloat16* __restrict__ in, __hip_bfloat16* __restrict__ out,
    const __hip_bfloat16* __restrict__ wb, const float* __restrict__ bias) {
  constexpr int HO = HIN - 2;
  constexpr int NPH = CIN / 32;
  constexpr int NF = COUT / 16;
  constexpr int TX = 18;
  constexpr int SLOTS = TX * TX * 4;
  constexpr int ITERS = (SLOTS + 255) / 256;
  constexpr int ROWSTRIDE = TX * 4 * 16;
  __shared__ char lds[ITERS * 256 * 16];

  const int zb = blockIdx.z;
  const __hip_bfloat16* ip = in + (size_t)zb * HIN * HIN * CIN;
  __hip_bfloat16* op = out + (size_t)zb * HO * HO * COUT;
  const int lane = threadIdx.x & 63;
  const int wave = threadIdx.x >> 6;
  const int x0 = blockIdx.x * 16;
  const int y0 = blockIdx.y * 16;

  int abase[3];
#pragma unroll
  for (int kx = 0; kx < 3; ++kx) {
    int x = (lane & 15) + kx;
    int slot = (lane >> 4) ^ swz4(x);
    abase[kx] = (x * 4 + slot) * 16 + wave * 4 * ROWSTRIDE;
  }

  float bv[NF];
#pragma unroll
  for (int n = 0; n < NF; ++n) bv[n] = bias[n * 16 + (lane & 15)];
  float4_t acc[4][NF];
#pragma unroll
  for (int m = 0; m < 4; ++m)
#pragma unroll
    for (int n = 0; n < NF; ++n) acc[m][n] = {bv[n], bv[n], bv[n], bv[n]};

#pragma unroll
  for (int ph = 0; ph < NPH; ++ph) {
#pragma unroll
    for (int i = 0; i < ITERS; ++i) {
      int sbase = i * 256 + wave * 64;
      int slot = sbase + lane;
      slot = slot < SLOTS ? slot : SLOTS - 1;
      int pix = slot >> 2, scb = slot & 3;
      int y = pix / TX, x = pix - y * TX;
      int cb = scb ^ swz4(x);
      int gy = min(y0 + y, HIN - 1), gx = min(x0 + x, HIN - 1);
      const __hip_bfloat16* src = ip + ((size_t)gy * HIN + gx) * CIN + ph * 32 + cb * 8;
      gld16(src, lds + (size_t)sbase * 16);
    }
    __syncthreads();

#pragma unroll
    for (int t = 0; t < 9; ++t) {
      const int ky = t / 3, kx = t % 3;
      short8_t B[NF];
#pragma unroll
      for (int n = 0; n < NF; ++n)
        B[n] = *reinterpret_cast<const short8_t*>(
            wb + (size_t)(((t * NPH + ph) * NF + n) * 64 + lane) * 8);
#pragma unroll
      for (int m = 0; m < 4; ++m) {
        short8_t A = *reinterpret_cast<const short8_t*>(
            lds + abase[kx] + (m + ky) * ROWSTRIDE);
#pragma unroll
        for (int n = 0; n < NF; ++n)
          acc[m][n] = __builtin_amdgcn_mfma_f32_16x16x32_bf16(A, B[n], acc[m][n], 0, 0, 0);
      }
    }
    if (ph + 1 < NPH) __syncthreads();
  }

#pragma unroll
  for (int m = 0; m < 4; ++m) {
    int yy = y0 + wave * 4 + m;
    if (yy < HO) {
#pragma unroll
      for (int r = 0; r < 4; ++r) {
        int xx = x0 + (lane >> 4) * 4 + r;
        if (xx < HO) {
#pragma unroll
          for (int n = 0; n < NF; ++n) {
            float v = acc[m][n][r];
            v = v > 0.0f ? v : 0.0f;
            op[((size_t)yy * HO + xx) * COUT + n * 16 + (lane & 15)] = __float2bfloat16(v);
          }
        }
      }
    }
  }
}

// ---------------- conv4: 3x3 32->16 MFMA + sigmoid + pixel_shuffle(r=4) ----------------
__global__ __launch_bounds__(256, 4) void conv4_mfma(
    const __hip_bfloat16* __restrict__ in, float* __restrict__ out,
    const __hip_bfloat16* __restrict__ wb, const float* __restrict__ bias, int bBase) {
  constexpr int CIN = 32, HIN = HO3;
  constexpr int TX = 18;
  constexpr int SLOTS = TX * TX * 4;
  constexpr int ITERS = (SLOTS + 255) / 256;
  constexpr int ROWSTRIDE = TX * 4 * 16;
  __shared__ char lds[ITERS * 256 * 16];

  const int zb = blockIdx.z;
  const __hip_bfloat16* ip = in + (size_t)zb * HIN * HIN * CIN;
  const int lane = threadIdx.x & 63;
  const int wave = threadIdx.x >> 6;
  const int x0 = blockIdx.x * 16;
  const int y0 = blockIdx.y * 16;

#pragma unroll
  for (int i = 0; i < ITERS; ++i) {
    int sbase = i * 256 + wave * 64;
    int slot = sbase + lane;
    slot = slot < SLOTS ? slot : SLOTS - 1;
    int pix = slot >> 2, scb = slot & 3;
    int y = pix / TX, x = pix - y * TX;
    int cb = scb ^ swz4(x);
    int gy = min(y0 + y, HIN - 1), gx = min(x0 + x, HIN - 1);
    const __hip_bfloat16* src = ip + ((size_t)gy * HIN + gx) * CIN + cb * 8;
    gld16(src, lds + (size_t)sbase * 16);
  }
  __syncthreads();

  int abase[3];
#pragma unroll
  for (int kx = 0; kx < 3; ++kx) {
    int x = (lane & 15) + kx;
    int slot = (lane >> 4) ^ swz4(x);
    abase[kx] = (x * 4 + slot) * 16 + wave * 4 * ROWSTRIDE;
  }

  float bv = bias[lane & 15];
  float4_t acc[4];
#pragma unroll
  for (int m = 0; m < 4; ++m) acc[m] = {bv, bv, bv, bv};

#pragma unroll
  for (int t = 0; t < 9; ++t) {
    const int ky = t / 3, kx = t % 3;
    short8_t B = *reinterpret_cast<const short8_t*>(wb + (size_t)(t * 64 + lane) * 8);
#pragma unroll
    for (int m = 0; m < 4; ++m) {
      short8_t A = *reinterpret_cast<const short8_t*>(
          lds + abase[kx] + (m + ky) * ROWSTRIDE);
      acc[m] = __builtin_amdgcn_mfma_f32_16x16x32_bf16(A, B, acc[m], 0, 0, 0);
    }
  }
  float* ob = out + (size_t)(bBase + zb) * 1024 * 1024;
  const int oc = lane & 15;
#pragma unroll
  for (int m = 0; m < 4; ++m) {
    int yy = y0 + wave * 4 + m;
#pragma unroll
    for (int r = 0; r < 4; ++r) {
      int xx = x0 + (lane >> 4) * 4 + r;
      float v = 1.0f / (1.0f + expf(-acc[m][r]));
      ob[(size_t)(yy * 4 + (oc >> 2)) * 1024 + xx * 4 + (oc & 3)] = v;
    }
  }
}

extern "C" void kernel_launch(void* const* d_in, const int* in_sizes, int n_in,
                              void* d_out, int out_size, void* d_ws, size_t ws_size,
                              hipStream_t stream) {
  const float* x  = (const float*)d_in[0];
  const float* W1 = (const float*)d_in[1];
  const float* b1 = (const float*)d_in[2];
  const float* W2 = (const float*)d_in[3];
  const float* b2 = (const float*)d_in[4];
  const float* W3 = (const float*)d_in[5];
  const float* b3 = (const float*)d_in[6];
  const float* W4 = (const float*)d_in[7];
  const float* b4 = (const float*)d_in[8];
  float* out = (float*)d_out;

  __hip_bfloat16* wr1 = (__hip_bfloat16*)d_ws;   // 2048 elems
  __hip_bfloat16* wr2 = wr1 + 2048;              // 18432
  __hip_bfloat16* wr3 = wr2 + 18432;             // 9216
  __hip_bfloat16* wr4 = wr3 + 9216;              // 4608
  char* base = (char*)d_ws + 131072;

  const size_t xp_sz = (size_t)WPD * WPD * sizeof(float);
  const size_t h2_sz = (size_t)HO2 * HO2 * 32 * sizeof(__hip_bfloat16);
  const size_t h3_sz = (size_t)HO3 * HO3 * 32 * sizeof(__hip_bfloat16);
  const size_t per_b = xp_sz + h2_sz + h3_sz;    // ~8.87 MB/batch

  int g = (int)((ws_size - 131072) / per_b);
  if (g > 16) g = 16;
  if (g < 1) g = 1;

  float* xp = (float*)base;
  __hip_bfloat16* h2 = (__hip_bfloat16*)(base + (size_t)g * xp_sz);
  __hip_bfloat16* h3 = (__hip_bfloat16*)((char*)h2 + (size_t)g * h2_sz);

  repack_w1<<<8, 256, 0, stream>>>(W1, wr1);
  repack_w<<<72, 256, 0, stream>>>(W2, wr2, 64, 32);
  repack_w<<<36, 256, 0, stream>>>(W3, wr3, 32, 32);
  repack_w<<<18, 256, 0, stream>>>(W4, wr4, 32, 16);

  for (int bBase = 0; bBase < 16; bBase += g) {
    int gc = min(g, 16 - bBase);
    size_t tot = (size_t)gc * WPD * WPD;
    int fillBlocks = (int)min((tot + 255) / 256, (size_t)2048);
    pad_fill_kernel<<<fillBlocks, 256, 0, stream>>>(x, xp, bBase, gc);
    extrap_kernel<<<gc, 256, 0, stream>>>(xp);
    conv12_mfma<<<dim3(17, 17, gc), 256, 0, stream>>>(xp, h2, wr1, b1, wr2, b2);
    conv3x3_mfma<32, 32, HO2><<<dim3(17, 17, gc), 256, 0, stream>>>(h2, h3, wr3, b3);
    conv4_mfma<<<dim3(16, 16, gc), 256, 0, stream>>>(h3, out, wr4, b4, bBase);
  }
}